// Round 1
// baseline (301.597 us; speedup 1.0000x reference)
//
#include <hip/hip_runtime.h>
#include <math.h>

#define N_NODES 21
#define PI_D 3.141592653589793

__global__ __launch_bounds__(256) void actor_fused_kernel(
    const float* __restrict__ state24,
    const float* __restrict__ Wl1, const float* __restrict__ Wr1,
    const float* __restrict__ att1, const float* __restrict__ b1,
    const float* __restrict__ Wl2, const float* __restrict__ Wr2,
    const float* __restrict__ att2, const float* __restrict__ b2,
    const float* __restrict__ fc1_w, const float* __restrict__ fc1_b,
    const float* __restrict__ fc2_w, const float* __restrict__ fc2_b,
    const float* __restrict__ fc3_w, const float* __restrict__ fc3_b,
    float* __restrict__ out, int B)
{
    const int b = blockIdx.x;
    if (b >= B) return;
    const int tid = threadIdx.x;

    // ---- LDS layout ----
    __shared__ float sinL[20], cosL[20], laserL[20], robotL[4];
    __shared__ float gl1[21 * 257];      // layer-1 source transform, stride 257 (pad)
    __shared__ float gr1[21 * 257];      // layer-1 target transform; reused as h1 after layer 1
    __shared__ float attL[256];          // att1 [4][64]
    __shared__ float eP[1764];           // e / exp(e - max), layout [h][i][j]
    __shared__ float rs1[84];            // row sums, [h*21 + i]
    __shared__ float gl2[21 * 65];       // layer-2 source transform, stride 65 (pad)
    __shared__ float gr2[21 * 65];
    __shared__ float att2L[64];
    __shared__ float e2[441];            // [i][j]
    __shared__ float rs2[21];
    __shared__ float part[4][64];
    __shared__ float nfv[64];
    __shared__ float ha[256];
    __shared__ float hb[256];

    // ---- setup: node scalar features ----
    if (tid < 20) {
        double step = (PI_D + 0.03) / 20.0;
        double bound = -PI_D / 2.0 - 0.03 + (double)tid * step;
        float ang = (float)bound + (float)(PI_D / 20.0);
        sinL[tid] = sinf(ang);
        cosL[tid] = cosf(ang);
        laserL[tid] = state24[b * 24 + tid] * 0.1f;   // / MAX_RANGE
    }
    if (tid >= 32 && tid < 36) robotL[tid - 32] = state24[b * 24 + 20 + (tid - 32)];
    attL[tid] = att1[tid];
    if (tid < 64) att2L[tid] = att2[tid];
    __syncthreads();

    // ---- layer-1 transforms: gl1/gr1 [21][256] (x @ Wl1 / x @ Wr1) ----
    {
        float wl[7], wr[7];
        #pragma unroll
        for (int k = 0; k < 7; k++) { wl[k] = Wl1[k * 256 + tid]; wr[k] = Wr1[k * 256 + tid]; }
        #pragma unroll
        for (int n = 0; n < 20; n++) {
            float l = laserL[n], s = sinL[n], c = cosL[n];
            gl1[n * 257 + tid] = l * wl[0] + s * wl[1] + c * wl[2];
            gr1[n * 257 + tid] = l * wr[0] + s * wr[1] + c * wr[2];
        }
        float r0 = robotL[0], r1 = robotL[1], r2 = robotL[2], r3 = robotL[3];
        gl1[20 * 257 + tid] = r0 * wl[3] + r1 * wl[4] + r2 * wl[5] + r3 * wl[6];
        gr1[20 * 257 + tid] = r0 * wr[3] + r1 * wr[4] + r2 * wr[5] + r3 * wr[6];
    }
    __syncthreads();

    // ---- layer-1 attention logits: e[h][i][j] = att1[h] . lrelu(gl1[j] + gr1[i]) ----
    for (int it = 0; it < 7; ++it) {
        int t = it * 256 + tid;
        if (t < 1764) {
            int h = t / 441;
            int p = t - h * 441;
            int i = p / 21;
            int j = p - i * 21;
            const float* gA = &gl1[j * 257 + h * 64];
            const float* gB = &gr1[i * 257 + h * 64];
            const float* aa = &attL[h * 64];
            float a0 = 0.f, a1 = 0.f, a2 = 0.f, a3 = 0.f;
            #pragma unroll
            for (int d = 0; d < 64; d += 4) {
                float v0 = gA[d + 0] + gB[d + 0]; v0 = v0 > 0.f ? v0 : 0.2f * v0;
                float v1 = gA[d + 1] + gB[d + 1]; v1 = v1 > 0.f ? v1 : 0.2f * v1;
                float v2 = gA[d + 2] + gB[d + 2]; v2 = v2 > 0.f ? v2 : 0.2f * v2;
                float v3 = gA[d + 3] + gB[d + 3]; v3 = v3 > 0.f ? v3 : 0.2f * v3;
                a0 = fmaf(aa[d + 0], v0, a0);
                a1 = fmaf(aa[d + 1], v1, a1);
                a2 = fmaf(aa[d + 2], v2, a2);
                a3 = fmaf(aa[d + 3], v3, a3);
            }
            eP[t] = (a0 + a1) + (a2 + a3);
        }
    }
    __syncthreads();

    // ---- softmax over j (rows = [h][i], 84 rows of 21) ----
    if (tid < 84) {
        const int base = tid * 21;
        float m = -1e30f;
        for (int j = 0; j < 21; j++) m = fmaxf(m, eP[base + j]);
        float s = 0.f;
        for (int j = 0; j < 21; j++) { float v = expf(eP[base + j] - m); eP[base + j] = v; s += v; }
        rs1[tid] = s;
    }
    __syncthreads();

    // ---- layer-1 aggregation + bias + ELU -> h1 (stored into gr1 buffer) ----
    {
        int h = tid >> 6;
        float bb = b1[tid];
        for (int i = 0; i < 21; i++) {
            const float* pr = &eP[(h * 21 + i) * 21];
            float acc = 0.f;
            #pragma unroll
            for (int j = 0; j < 21; j++) acc = fmaf(pr[j], gl1[j * 257 + tid], acc);
            float val = acc / rs1[h * 21 + i] + bb;
            gr1[i * 257 + tid] = val > 0.f ? val : expm1f(val);
        }
    }
    __syncthreads();

    // ---- layer-2 transforms: gl2/gr2 [21][64] = h1 @ Wl2 / h1 @ Wr2 ----
    {
        int c = tid & 63, g = tid >> 6;
        float accL[6] = {0, 0, 0, 0, 0, 0}, accR[6] = {0, 0, 0, 0, 0, 0};
        for (int k = 0; k < 256; k++) {
            float wl = Wl2[k * 64 + c];
            float wr = Wr2[k * 64 + c];
            #pragma unroll
            for (int m = 0; m < 6; m++) {
                int n = g + 4 * m;
                if (n < 21) {
                    float hv = gr1[n * 257 + k];
                    accL[m] = fmaf(hv, wl, accL[m]);
                    accR[m] = fmaf(hv, wr, accR[m]);
                }
            }
        }
        #pragma unroll
        for (int m = 0; m < 6; m++) {
            int n = g + 4 * m;
            if (n < 21) { gl2[n * 65 + c] = accL[m]; gr2[n * 65 + c] = accR[m]; }
        }
    }
    __syncthreads();

    // ---- layer-2 attention logits (1 head) ----
    for (int it = 0; it < 2; ++it) {
        int t = it * 256 + tid;
        if (t < 441) {
            int i = t / 21;
            int j = t - i * 21;
            const float* gA = &gl2[j * 65];
            const float* gB = &gr2[i * 65];
            float a0 = 0.f, a1 = 0.f, a2 = 0.f, a3 = 0.f;
            #pragma unroll
            for (int d = 0; d < 64; d += 4) {
                float v0 = gA[d + 0] + gB[d + 0]; v0 = v0 > 0.f ? v0 : 0.2f * v0;
                float v1 = gA[d + 1] + gB[d + 1]; v1 = v1 > 0.f ? v1 : 0.2f * v1;
                float v2 = gA[d + 2] + gB[d + 2]; v2 = v2 > 0.f ? v2 : 0.2f * v2;
                float v3 = gA[d + 3] + gB[d + 3]; v3 = v3 > 0.f ? v3 : 0.2f * v3;
                a0 = fmaf(att2L[d + 0], v0, a0);
                a1 = fmaf(att2L[d + 1], v1, a1);
                a2 = fmaf(att2L[d + 2], v2, a2);
                a3 = fmaf(att2L[d + 3], v3, a3);
            }
            e2[t] = (a0 + a1) + (a2 + a3);
        }
    }
    __syncthreads();

    if (tid < 21) {
        const int base = tid * 21;
        float m = -1e30f;
        for (int j = 0; j < 21; j++) m = fmaxf(m, e2[base + j]);
        float s = 0.f;
        for (int j = 0; j < 21; j++) { float v = expf(e2[base + j] - m); e2[base + j] = v; s += v; }
        rs2[tid] = s;
    }
    __syncthreads();

    // ---- layer-2 aggregation + mean pool partials ----
    {
        int d = tid & 63, g = tid >> 6;
        float sacc = 0.f;
        #pragma unroll
        for (int m = 0; m < 6; m++) {
            int i = g + 4 * m;
            if (i < 21) {
                const float* pr = &e2[i * 21];
                float acc = 0.f;
                #pragma unroll
                for (int j = 0; j < 21; j++) acc = fmaf(pr[j], gl2[j * 65 + d], acc);
                sacc += acc / rs2[i];
            }
        }
        part[g][d] = sacc;
    }
    __syncthreads();
    if (tid < 64) {
        nfv[tid] = (part[0][tid] + part[1][tid] + part[2][tid] + part[3][tid]) * (1.f / 21.f) + b2[tid];
    }
    __syncthreads();

    // ---- FC1 (64 -> 256) + ReLU ----
    {
        float acc = fc1_b[tid];
        #pragma unroll
        for (int k = 0; k < 64; k++) acc = fmaf(nfv[k], fc1_w[k * 256 + tid], acc);
        ha[tid] = fmaxf(acc, 0.f);
    }
    __syncthreads();

    // ---- FC2 (256 -> 256) + ReLU ----
    {
        float acc = fc2_b[tid];
        for (int k = 0; k < 256; k++) acc = fmaf(ha[k], fc2_w[k * 256 + tid], acc);
        hb[tid] = fmaxf(acc, 0.f);
    }
    __syncthreads();

    // ---- FC3 (256 -> 2) + tanh, wave-reduce ----
    if (tid < 128) {
        int o = tid >> 6, l = tid & 63;
        float s = 0.f;
        #pragma unroll
        for (int m = 0; m < 4; m++) { int k = l + 64 * m; s = fmaf(hb[k], fc3_w[k * 2 + o], s); }
        #pragma unroll
        for (int off = 32; off >= 1; off >>= 1) s += __shfl_down(s, off, 64);
        if (l == 0) out[b * 2 + o] = tanhf(s + fc3_b[o]);
    }
}

extern "C" void kernel_launch(void* const* d_in, const int* in_sizes, int n_in,
                              void* d_out, int out_size, void* d_ws, size_t ws_size,
                              hipStream_t stream) {
    const float* state24 = (const float*)d_in[0];
    const float* Wl1 = (const float*)d_in[1];
    const float* Wr1 = (const float*)d_in[2];
    const float* att1 = (const float*)d_in[3];
    const float* b1 = (const float*)d_in[4];
    const float* Wl2 = (const float*)d_in[5];
    const float* Wr2 = (const float*)d_in[6];
    const float* att2 = (const float*)d_in[7];
    const float* b2 = (const float*)d_in[8];
    const float* fc1_w = (const float*)d_in[9];
    const float* fc1_b = (const float*)d_in[10];
    const float* fc2_w = (const float*)d_in[11];
    const float* fc2_b = (const float*)d_in[12];
    const float* fc3_w = (const float*)d_in[13];
    const float* fc3_b = (const float*)d_in[14];
    float* out = (float*)d_out;

    int B = in_sizes[0] / 24;
    actor_fused_kernel<<<B, 256, 0, stream>>>(
        state24, Wl1, Wr1, att1, b1, Wl2, Wr2, att2, b2,
        fc1_w, fc1_b, fc2_w, fc2_b, fc3_w, fc3_b, out, B);
}

// Round 3
// 171.156 us; speedup vs baseline: 1.7621x; 1.7621x over previous
//
#include <hip/hip_runtime.h>
#include <hip/hip_fp16.h>
#include <math.h>

#define PI_D 3.141592653589793

typedef _Float16 h2 __attribute__((ext_vector_type(2)));

// stride constants (in units noted)
#define STR1 260     // gl1h/gr1h row stride in halves (pad: 256+4; /2=130 even -> 8B aligned rows)
#define STR1H 130    // same, in h2 units
#define STR2 66      // gl2/gr2 row stride in floats (row bytes 264, 8B aligned)

static __device__ __forceinline__ h2 pack_h2(float a, float b) {
#if __has_builtin(__builtin_amdgcn_cvt_pkrtz)
    return __builtin_bit_cast(h2, __builtin_amdgcn_cvt_pkrtz(a, b));
#else
    h2 r; r.x = (_Float16)a; r.y = (_Float16)b; return r;
#endif
}

static __device__ __forceinline__ float fdot2(h2 a, h2 b, float c) {
#if __has_builtin(__builtin_amdgcn_fdot2)
    return __builtin_amdgcn_fdot2(__builtin_bit_cast(__fp16 __attribute__((ext_vector_type(2))), a),
                                  __builtin_bit_cast(__fp16 __attribute__((ext_vector_type(2))), b),
                                  c, false);
#else
    return fmaf((float)a.x, (float)b.x, fmaf((float)a.y, (float)b.y, c));
#endif
}

__global__ __launch_bounds__(256, 5) void actor_fused_kernel(
    const float* __restrict__ state24,
    const float* __restrict__ Wl1, const float* __restrict__ Wr1,
    const float* __restrict__ att1, const float* __restrict__ b1,
    const float* __restrict__ Wl2, const float* __restrict__ Wr2,
    const float* __restrict__ att2, const float* __restrict__ b2,
    const float* __restrict__ fc1_w, const float* __restrict__ fc1_b,
    const float* __restrict__ fc2_w, const float* __restrict__ fc2_b,
    const float* __restrict__ fc3_w, const float* __restrict__ fc3_b,
    float* __restrict__ out, int B)
{
    const int bix = blockIdx.x;
    if (bix >= B) return;
    const int tid = threadIdx.x;

    __shared__ float sinL[20], cosL[20], laserL[20], robotL[4];
    __shared__ float attL[256];
    __shared__ float att2L[64];
    __shared__ __align__(16) _Float16 gr1h[21 * STR1];   // r-transform, then h1 (fp16 pairs)
    __shared__ __align__(16) union {
        struct { _Float16 gl1h[21 * STR1]; float eP[1764]; } p1;             // layer-1 phase
        struct { float gl2[21 * STR2]; float gr2[21 * STR2]; float e2[441];  // layer-2 + FC phase
                 float part[4][64]; float nfv[64]; float ha[256]; float hb[256]; } p2;
    } U;

    // ---- setup ----
    if (tid < 20) {
        double step = (PI_D + 0.03) / 20.0;
        float bound = (float)(-PI_D / 2.0 - 0.03 + (double)tid * step);
        float ang = bound + (float)(PI_D / 20.0);
        sinL[tid] = sinf(ang);
        cosL[tid] = cosf(ang);
        laserL[tid] = state24[bix * 24 + tid] * 0.1f;
    }
    if (tid >= 32 && tid < 36) robotL[tid - 32] = state24[bix * 24 + 20 + (tid - 32)];
    attL[tid] = att1[tid];
    if (tid < 64) att2L[tid] = att2[tid];
    __syncthreads();

    // ---- layer-1 transforms -> fp16 LDS ----
    {
        float wl[7], wr[7];
        #pragma unroll
        for (int k = 0; k < 7; k++) { wl[k] = Wl1[k * 256 + tid]; wr[k] = Wr1[k * 256 + tid]; }
        #pragma unroll
        for (int n = 0; n < 20; n++) {
            float l = laserL[n], s = sinL[n], c = cosL[n];
            U.p1.gl1h[n * STR1 + tid] = (_Float16)(l * wl[0] + s * wl[1] + c * wl[2]);
            gr1h[n * STR1 + tid]     = (_Float16)(l * wr[0] + s * wr[1] + c * wr[2]);
        }
        float r0 = robotL[0], r1 = robotL[1], r2 = robotL[2], r3 = robotL[3];
        U.p1.gl1h[20 * STR1 + tid] = (_Float16)(r0 * wl[3] + r1 * wl[4] + r2 * wl[5] + r3 * wl[6]);
        gr1h[20 * STR1 + tid]     = (_Float16)(r0 * wr[3] + r1 * wr[4] + r2 * wr[5] + r3 * wr[6]);
    }
    __syncthreads();

    // ---- layer-1 logits: lrelu(x) = 0.6x + 0.4|x| ----
    for (int it = 0; it < 7; ++it) {
        int t = it * 256 + tid;
        if (t < 1764) {
            int h = t / 441;
            int p = t - h * 441;
            int i = p / 21;
            int j = p - i * 21;
            const h2* gA = (const h2*)U.p1.gl1h + j * STR1H + h * 32;
            const h2* gB = (const h2*)gr1h + i * STR1H + h * 32;
            const float2* aa = (const float2*)attL + h * 32;
            float l0 = 0.f, l1 = 0.f, m0 = 0.f, m1 = 0.f;
            #pragma unroll
            for (int dp = 0; dp < 32; ++dp) {
                h2 xp = gA[dp] + gB[dp];
                float2 a = aa[dp];
                float x0 = (float)xp.x, x1 = (float)xp.y;
                l0 = fmaf(a.x, x0, l0); m0 = fmaf(a.x, fabsf(x0), m0);
                l1 = fmaf(a.y, x1, l1); m1 = fmaf(a.y, fabsf(x1), m1);
            }
            U.p1.eP[t] = 0.6f * (l0 + l1) + 0.4f * (m0 + m1);
        }
    }
    __syncthreads();

    // ---- softmax over j + pre-normalize (rows = [h][i]) ----
    if (tid < 84) {
        float* row = U.p1.eP + tid * 21;
        float m = row[0];
        #pragma unroll
        for (int j = 1; j < 21; j++) m = fmaxf(m, row[j]);
        float s = 0.f;
        #pragma unroll
        for (int j = 0; j < 21; j++) { float v = __expf(row[j] - m); row[j] = v; s += v; }
        float r = 1.f / s;
        #pragma unroll
        for (int j = 0; j < 21; j++) row[j] *= r;
    }
    __syncthreads();

    // ---- layer-1 aggregation + bias + ELU -> h1 (fp16, into gr1h) ----
    {
        int p = tid & 127, gi = tid >> 7;
        int h = p >> 5;
        float2 bb = ((const float2*)b1)[p];
        const h2* gcol = (const h2*)U.p1.gl1h + p;
        for (int i = gi; i < 21; i += 2) {
            const float* al = U.p1.eP + (h * 21 + i) * 21;
            float a0 = 0.f, a1 = 0.f;
            #pragma unroll
            for (int j = 0; j < 21; ++j) {
                float alpha = al[j];
                h2 gv = gcol[j * STR1H];
                a0 = fmaf(alpha, (float)gv.x, a0);
                a1 = fmaf(alpha, (float)gv.y, a1);
            }
            float v0 = a0 + bb.x, v1 = a1 + bb.y;
            v0 = v0 > 0.f ? v0 : __expf(v0) - 1.f;
            v1 = v1 > 0.f ? v1 : __expf(v1) - 1.f;
            h2 o; o.x = (_Float16)v0; o.y = (_Float16)v1;
            ((h2*)gr1h)[i * STR1H + p] = o;
        }
    }
    __syncthreads();

    // ---- layer-2 transforms via v_dot2_f32_f16 ----
    {
        int c = tid & 63, g = tid >> 6;
        float accL[6] = {0, 0, 0, 0, 0, 0}, accR[6] = {0, 0, 0, 0, 0, 0};
        const h2* hrow = (const h2*)gr1h;
        #pragma unroll 4
        for (int k = 0; k < 128; ++k) {
            float wl0 = Wl2[(2 * k) * 64 + c], wl1 = Wl2[(2 * k + 1) * 64 + c];
            float wr0 = Wr2[(2 * k) * 64 + c], wr1 = Wr2[(2 * k + 1) * 64 + c];
            h2 wlp = pack_h2(wl0, wl1);
            h2 wrp = pack_h2(wr0, wr1);
            #pragma unroll
            for (int m = 0; m < 6; ++m) {
                int n = g + 4 * m;
                if (n < 21) {
                    h2 hv = hrow[n * STR1H + k];
                    accL[m] = fdot2(hv, wlp, accL[m]);
                    accR[m] = fdot2(hv, wrp, accR[m]);
                }
            }
        }
        #pragma unroll
        for (int m = 0; m < 6; ++m) {
            int n = g + 4 * m;
            if (n < 21) { U.p2.gl2[n * STR2 + c] = accL[m]; U.p2.gr2[n * STR2 + c] = accR[m]; }
        }
    }
    __syncthreads();

    // ---- layer-2 logits (1 head), abs-trick ----
    for (int it = 0; it < 2; ++it) {
        int t = it * 256 + tid;
        if (t < 441) {
            int i = t / 21;
            int j = t - i * 21;
            const float2* gA = (const float2*)(U.p2.gl2 + j * STR2);
            const float2* gB = (const float2*)(U.p2.gr2 + i * STR2);
            const float2* aa = (const float2*)att2L;
            float l0 = 0.f, l1 = 0.f, m0 = 0.f, m1 = 0.f;
            #pragma unroll
            for (int dp = 0; dp < 32; ++dp) {
                float2 va = gA[dp], vb = gB[dp], a = aa[dp];
                float x0 = va.x + vb.x, x1 = va.y + vb.y;
                l0 = fmaf(a.x, x0, l0); m0 = fmaf(a.x, fabsf(x0), m0);
                l1 = fmaf(a.y, x1, l1); m1 = fmaf(a.y, fabsf(x1), m1);
            }
            U.p2.e2[t] = 0.6f * (l0 + l1) + 0.4f * (m0 + m1);
        }
    }
    __syncthreads();

    if (tid < 21) {
        float* row = U.p2.e2 + tid * 21;
        float m = row[0];
        #pragma unroll
        for (int j = 1; j < 21; j++) m = fmaxf(m, row[j]);
        float s = 0.f;
        #pragma unroll
        for (int j = 0; j < 21; j++) { float v = __expf(row[j] - m); row[j] = v; s += v; }
        float r = 1.f / s;
        #pragma unroll
        for (int j = 0; j < 21; j++) row[j] *= r;
    }
    __syncthreads();

    // ---- layer-2 aggregation + mean-pool partials ----
    {
        int d = tid & 63, g = tid >> 6;
        float sacc = 0.f;
        #pragma unroll
        for (int m = 0; m < 6; ++m) {
            int i = g + 4 * m;
            if (i < 21) {
                const float* al = U.p2.e2 + i * 21;
                float acc = 0.f;
                #pragma unroll
                for (int j = 0; j < 21; ++j) acc = fmaf(al[j], U.p2.gl2[j * STR2 + d], acc);
                sacc += acc;
            }
        }
        U.p2.part[g][d] = sacc;
    }
    __syncthreads();
    if (tid < 64) {
        U.p2.nfv[tid] = (U.p2.part[0][tid] + U.p2.part[1][tid] + U.p2.part[2][tid] + U.p2.part[3][tid])
                        * (1.f / 21.f) + b2[tid];
    }
    __syncthreads();

    // ---- FC1 (64 -> 256) + ReLU ----
    {
        float acc = fc1_b[tid];
        #pragma unroll
        for (int k = 0; k < 64; k++) acc = fmaf(U.p2.nfv[k], fc1_w[k * 256 + tid], acc);
        U.p2.ha[tid] = fmaxf(acc, 0.f);
    }
    __syncthreads();

    // ---- FC2 (256 -> 256) + ReLU ----
    {
        float acc = fc2_b[tid];
        #pragma unroll 4
        for (int k = 0; k < 256; k++) acc = fmaf(U.p2.ha[k], fc2_w[k * 256 + tid], acc);
        U.p2.hb[tid] = fmaxf(acc, 0.f);
    }
    __syncthreads();

    // ---- FC3 (256 -> 2) + tanh ----
    if (tid < 128) {
        int o = tid >> 6, l = tid & 63;
        float s = 0.f;
        #pragma unroll
        for (int m = 0; m < 4; m++) { int k = l + 64 * m; s = fmaf(U.p2.hb[k], fc3_w[k * 2 + o], s); }
        #pragma unroll
        for (int off = 32; off >= 1; off >>= 1) s += __shfl_down(s, off, 64);
        if (l == 0) out[bix * 2 + o] = tanhf(s + fc3_b[o]);
    }
}

extern "C" void kernel_launch(void* const* d_in, const int* in_sizes, int n_in,
                              void* d_out, int out_size, void* d_ws, size_t ws_size,
                              hipStream_t stream) {
    const float* state24 = (const float*)d_in[0];
    const float* Wl1 = (const float*)d_in[1];
    const float* Wr1 = (const float*)d_in[2];
    const float* att1 = (const float*)d_in[3];
    const float* b1 = (const float*)d_in[4];
    const float* Wl2 = (const float*)d_in[5];
    const float* Wr2 = (const float*)d_in[6];
    const float* att2 = (const float*)d_in[7];
    const float* b2 = (const float*)d_in[8];
    const float* fc1_w = (const float*)d_in[9];
    const float* fc1_b = (const float*)d_in[10];
    const float* fc2_w = (const float*)d_in[11];
    const float* fc2_b = (const float*)d_in[12];
    const float* fc3_w = (const float*)d_in[13];
    const float* fc3_b = (const float*)d_in[14];
    float* out = (float*)d_out;

    int B = in_sizes[0] / 24;
    actor_fused_kernel<<<B, 256, 0, stream>>>(
        state24, Wl1, Wr1, att1, b1, Wl2, Wr2, att2, b2,
        fc1_w, fc1_b, fc2_w, fc2_b, fc3_w, fc3_b, out, B);
}

// Round 4
// 136.624 us; speedup vs baseline: 2.2075x; 1.2528x over previous
//
#include <hip/hip_runtime.h>
#include <hip/hip_fp16.h>
#include <math.h>

#define PI_D 3.141592653589793

typedef _Float16 h2 __attribute__((ext_vector_type(2)));
typedef _Float16 h4 __attribute__((ext_vector_type(4)));
typedef unsigned short us4 __attribute__((ext_vector_type(4)));
typedef __fp16 f16v2 __attribute__((ext_vector_type(2)));

#define STR1 260     // gl1h/gr1h row stride in halves (even -> 8B-aligned rows)
#define STR1H 130    // in h2 units
#define STR1Q 65     // in h4 units
#define STR2 66      // gl2/gr2 row stride in floats

static __device__ __forceinline__ h2 pack_h2(float a, float b) {
    return __builtin_bit_cast(h2, __builtin_amdgcn_cvt_pkrtz(a, b));
}

static __device__ __forceinline__ float fdot2(h2 a, h2 b, float c) {
    return __builtin_amdgcn_fdot2(__builtin_bit_cast(f16v2, a),
                                  __builtin_bit_cast(f16v2, b), c, false);
}

static __device__ __forceinline__ h4 habs4(h4 x) {
    us4 u = __builtin_bit_cast(us4, x);
    us4 m = {0x7fff, 0x7fff, 0x7fff, 0x7fff};
    return __builtin_bit_cast(h4, (us4)(u & m));
}

__global__ __launch_bounds__(256, 4) void actor_fused_kernel(
    const float* __restrict__ state24,
    const float* __restrict__ Wl1, const float* __restrict__ Wr1,
    const float* __restrict__ att1, const float* __restrict__ b1,
    const float* __restrict__ Wl2, const float* __restrict__ Wr2,
    const float* __restrict__ att2, const float* __restrict__ b2,
    const float* __restrict__ fc1_w, const float* __restrict__ fc1_b,
    const float* __restrict__ fc2_w, const float* __restrict__ fc2_b,
    const float* __restrict__ fc3_w, const float* __restrict__ fc3_b,
    float* __restrict__ out, int B)
{
    const int bix = blockIdx.x;
    if (bix >= B) return;
    const int tid = threadIdx.x;

    __shared__ float sinL[20], cosL[20], laserL[20], robotL[4];
    __shared__ __align__(16) h2 attLh[128];      // att1 packed fp16, [h][32 pairs]
    __shared__ __align__(16) float att2L[64];
    __shared__ __align__(16) _Float16 gr1h[24 * STR1];   // r-transform, then h1 (24 rows: 21 + 3 zero-pad)
    __shared__ __align__(16) union {
        struct { _Float16 gl1h[21 * STR1]; float eP[1764]; } p1;
        struct { float gl2[24 * STR2]; float gr2[24 * STR2]; float e2[24 * 21];
                 float part[4][64]; float nfv[64]; float ha[256]; float hb[256]; } p2;
    } U;

    // ---- setup ----
    if (tid < 20) {
        double step = (PI_D + 0.03) / 20.0;
        float bound = (float)(-PI_D / 2.0 - 0.03 + (double)tid * step);
        float ang = bound + (float)(PI_D / 20.0);
        sinL[tid] = sinf(ang);
        cosL[tid] = cosf(ang);
        laserL[tid] = state24[bix * 24 + tid] * 0.1f;
    }
    if (tid >= 32 && tid < 36) robotL[tid - 32] = state24[bix * 24 + 20 + (tid - 32)];
    if (tid < 128) {
        float2 ap = ((const float2*)att1)[tid];
        attLh[tid] = pack_h2(ap.x, ap.y);
    }
    if (tid < 64) att2L[tid] = att2[tid];
    __syncthreads();

    // ---- layer-1 transforms -> fp16 LDS ----
    {
        float wl[7], wr[7];
        #pragma unroll
        for (int k = 0; k < 7; k++) { wl[k] = Wl1[k * 256 + tid]; wr[k] = Wr1[k * 256 + tid]; }
        #pragma unroll
        for (int n = 0; n < 20; n++) {
            float l = laserL[n], s = sinL[n], c = cosL[n];
            U.p1.gl1h[n * STR1 + tid] = (_Float16)(l * wl[0] + s * wl[1] + c * wl[2]);
            gr1h[n * STR1 + tid]     = (_Float16)(l * wr[0] + s * wr[1] + c * wr[2]);
        }
        float r0 = robotL[0], r1 = robotL[1], r2 = robotL[2], r3 = robotL[3];
        U.p1.gl1h[20 * STR1 + tid] = (_Float16)(r0 * wl[3] + r1 * wl[4] + r2 * wl[5] + r3 * wl[6]);
        gr1h[20 * STR1 + tid]     = (_Float16)(r0 * wr[3] + r1 * wr[4] + r2 * wr[5] + r3 * wr[6]);
    }
    __syncthreads();

    // ---- layer-1 logits: packed fp16, h = wave-uniform, att in registers ----
    {
        const int h = tid >> 6;           // wave-uniform head
        const int lane = tid & 63;
        h4 areg[16];
        const h4* attH4 = (const h4*)attLh + h * 16;
        #pragma unroll
        for (int q = 0; q < 16; ++q) areg[q] = attH4[q];

        for (int it = 0; it < 7; ++it) {
            int q = it * 64 + lane;
            if (q < 441) {
                int i = q / 21;
                int j = q - i * 21;
                const h4* gA4 = (const h4*)(U.p1.gl1h + j * STR1 + h * 64);
                const h4* gB4 = (const h4*)(gr1h + i * STR1 + h * 64);
                float l0 = 0.f, l1 = 0.f, m0 = 0.f, m1 = 0.f;
                #pragma unroll
                for (int dp = 0; dp < 16; ++dp) {
                    h4 x = gA4[dp] + gB4[dp];
                    h4 ax = habs4(x);
                    h2 xl = __builtin_shufflevector(x, x, 0, 1);
                    h2 xh = __builtin_shufflevector(x, x, 2, 3);
                    h2 al = __builtin_shufflevector(areg[dp], areg[dp], 0, 1);
                    h2 ah = __builtin_shufflevector(areg[dp], areg[dp], 2, 3);
                    h2 axl = __builtin_shufflevector(ax, ax, 0, 1);
                    h2 axh = __builtin_shufflevector(ax, ax, 2, 3);
                    l0 = fdot2(xl, al, l0); m0 = fdot2(axl, al, m0);
                    l1 = fdot2(xh, ah, l1); m1 = fdot2(axh, ah, m1);
                }
                U.p1.eP[h * 441 + q] = 0.6f * (l0 + l1) + 0.4f * (m0 + m1);
            }
        }
    }
    __syncthreads();

    // ---- softmax over j + pre-normalize (84 rows) ----
    if (tid < 84) {
        float* row = U.p1.eP + tid * 21;
        float m = row[0];
        #pragma unroll
        for (int j = 1; j < 21; j++) m = fmaxf(m, row[j]);
        float s = 0.f;
        #pragma unroll
        for (int j = 0; j < 21; j++) { float v = __expf(row[j] - m); row[j] = v; s += v; }
        float r = 1.f / s;
        #pragma unroll
        for (int j = 0; j < 21; j++) row[j] *= r;
    }
    __syncthreads();

    // ---- layer-1 aggregation + bias + ELU -> h1 (fp16, rows 0..20) + zero pad rows 21..23 ----
    {
        // zero-pad h1 rows 21..23 (k range 0..127 read by transform)
        h2 zz = {(_Float16)0.f, (_Float16)0.f};
        for (int z = tid; z < 384; z += 256)
            ((h2*)gr1h)[(21 + (z >> 7)) * STR1H + (z & 127)] = zz;

        int p = tid & 127, gi = tid >> 7;
        int h = p >> 5;
        float2 bb = ((const float2*)b1)[p];
        const h2* gcol = (const h2*)U.p1.gl1h + p;
        for (int i = gi; i < 21; i += 2) {
            const float* al = U.p1.eP + (h * 21 + i) * 21;
            float a0 = 0.f, a1 = 0.f;
            #pragma unroll
            for (int j = 0; j < 21; ++j) {
                float alpha = al[j];
                h2 gv = gcol[j * STR1H];
                a0 = fmaf(alpha, (float)gv.x, a0);
                a1 = fmaf(alpha, (float)gv.y, a1);
            }
            float v0 = a0 + bb.x, v1 = a1 + bb.y;
            v0 = v0 > 0.f ? v0 : __expf(v0) - 1.f;
            v1 = v1 > 0.f ? v1 : __expf(v1) - 1.f;
            h2 o; o.x = (_Float16)v0; o.y = (_Float16)v1;
            ((h2*)gr1h)[i * STR1H + p] = o;
        }
    }
    __syncthreads();

    // ---- layer-2 transforms via v_dot2_f32_f16 (uniform 6 rows, h4 LDS reads) ----
    {
        int c = tid & 63, g = tid >> 6;
        float accL[6] = {0, 0, 0, 0, 0, 0}, accR[6] = {0, 0, 0, 0, 0, 0};
        const h4* hrow4 = (const h4*)gr1h;
        const float* pwl = Wl2 + c;
        const float* pwr = Wr2 + c;
        #pragma unroll 2
        for (int kk = 0; kk < 64; ++kk) {
            float wl0 = pwl[(4 * kk + 0) * 64], wl1 = pwl[(4 * kk + 1) * 64];
            float wl2_ = pwl[(4 * kk + 2) * 64], wl3 = pwl[(4 * kk + 3) * 64];
            float wr0 = pwr[(4 * kk + 0) * 64], wr1 = pwr[(4 * kk + 1) * 64];
            float wr2_ = pwr[(4 * kk + 2) * 64], wr3 = pwr[(4 * kk + 3) * 64];
            h2 wlA = pack_h2(wl0, wl1), wlB = pack_h2(wl2_, wl3);
            h2 wrA = pack_h2(wr0, wr1), wrB = pack_h2(wr2_, wr3);
            #pragma unroll
            for (int m = 0; m < 6; ++m) {
                int n = g + 4 * m;           // 0..23, uniform
                h4 hv = hrow4[n * STR1Q + kk];
                h2 lo = __builtin_shufflevector(hv, hv, 0, 1);
                h2 hi = __builtin_shufflevector(hv, hv, 2, 3);
                accL[m] = fdot2(lo, wlA, accL[m]);
                accL[m] = fdot2(hi, wlB, accL[m]);
                accR[m] = fdot2(lo, wrA, accR[m]);
                accR[m] = fdot2(hi, wrB, accR[m]);
            }
        }
        #pragma unroll
        for (int m = 0; m < 6; ++m) {
            int n = g + 4 * m;
            U.p2.gl2[n * STR2 + c] = accL[m];
            U.p2.gr2[n * STR2 + c] = accR[m];
        }
    }
    __syncthreads();

    // ---- layer-2 logits (1 head), fp32 abs-trick ----
    for (int it = 0; it < 2; ++it) {
        int t = it * 256 + tid;
        if (t < 441) {
            int i = t / 21;
            int j = t - i * 21;
            const float2* gA = (const float2*)(U.p2.gl2 + j * STR2);
            const float2* gB = (const float2*)(U.p2.gr2 + i * STR2);
            const float2* aa = (const float2*)att2L;
            float l0 = 0.f, l1 = 0.f, m0 = 0.f, m1 = 0.f;
            #pragma unroll
            for (int dp = 0; dp < 32; ++dp) {
                float2 va = gA[dp], vb = gB[dp], a = aa[dp];
                float x0 = va.x + vb.x, x1 = va.y + vb.y;
                l0 = fmaf(a.x, x0, l0); m0 = fmaf(a.x, fabsf(x0), m0);
                l1 = fmaf(a.y, x1, l1); m1 = fmaf(a.y, fabsf(x1), m1);
            }
            U.p2.e2[t] = 0.6f * (l0 + l1) + 0.4f * (m0 + m1);
        }
    }
    __syncthreads();

    // ---- softmax-2 (21 rows) + zero rows 21..23 ----
    if (tid < 24) {
        float* row = U.p2.e2 + tid * 21;
        if (tid < 21) {
            float m = row[0];
            #pragma unroll
            for (int j = 1; j < 21; j++) m = fmaxf(m, row[j]);
            float s = 0.f;
            #pragma unroll
            for (int j = 0; j < 21; j++) { float v = __expf(row[j] - m); row[j] = v; s += v; }
            float r = 1.f / s;
            #pragma unroll
            for (int j = 0; j < 21; j++) row[j] *= r;
        } else {
            #pragma unroll
            for (int j = 0; j < 21; j++) row[j] = 0.f;
        }
    }
    __syncthreads();

    // ---- layer-2 aggregation + mean-pool partials (uniform 6 rows) ----
    {
        int d = tid & 63, g = tid >> 6;
        float sacc = 0.f;
        #pragma unroll
        for (int m = 0; m < 6; ++m) {
            int i = g + 4 * m;               // 0..23, rows >=21 have zero alpha
            const float* al = U.p2.e2 + i * 21;
            float acc = 0.f;
            #pragma unroll
            for (int j = 0; j < 21; ++j) acc = fmaf(al[j], U.p2.gl2[j * STR2 + d], acc);
            sacc += acc;
        }
        U.p2.part[g][d] = sacc;
    }
    __syncthreads();
    if (tid < 64) {
        U.p2.nfv[tid] = (U.p2.part[0][tid] + U.p2.part[1][tid] + U.p2.part[2][tid] + U.p2.part[3][tid])
                        * (1.f / 21.f) + b2[tid];
    }
    __syncthreads();

    // ---- FC1 (64 -> 256) + ReLU ----
    {
        float acc = fc1_b[tid];
        #pragma unroll
        for (int k = 0; k < 64; k++) acc = fmaf(U.p2.nfv[k], fc1_w[k * 256 + tid], acc);
        U.p2.ha[tid] = fmaxf(acc, 0.f);
    }
    __syncthreads();

    // ---- FC2 (256 -> 256) + ReLU ----
    {
        float acc = fc2_b[tid];
        #pragma unroll 8
        for (int k = 0; k < 256; k++) acc = fmaf(U.p2.ha[k], fc2_w[k * 256 + tid], acc);
        U.p2.hb[tid] = fmaxf(acc, 0.f);
    }
    __syncthreads();

    // ---- FC3 (256 -> 2) + tanh ----
    if (tid < 128) {
        int o = tid >> 6, l = tid & 63;
        float s = 0.f;
        #pragma unroll
        for (int m = 0; m < 4; m++) { int k = l + 64 * m; s = fmaf(U.p2.hb[k], fc3_w[k * 2 + o], s); }
        #pragma unroll
        for (int off = 32; off >= 1; off >>= 1) s += __shfl_down(s, off, 64);
        if (l == 0) out[bix * 2 + o] = tanhf(s + fc3_b[o]);
    }
}

extern "C" void kernel_launch(void* const* d_in, const int* in_sizes, int n_in,
                              void* d_out, int out_size, void* d_ws, size_t ws_size,
                              hipStream_t stream) {
    const float* state24 = (const float*)d_in[0];
    const float* Wl1 = (const float*)d_in[1];
    const float* Wr1 = (const float*)d_in[2];
    const float* att1 = (const float*)d_in[3];
    const float* b1 = (const float*)d_in[4];
    const float* Wl2 = (const float*)d_in[5];
    const float* Wr2 = (const float*)d_in[6];
    const float* att2 = (const float*)d_in[7];
    const float* b2 = (const float*)d_in[8];
    const float* fc1_w = (const float*)d_in[9];
    const float* fc1_b = (const float*)d_in[10];
    const float* fc2_w = (const float*)d_in[11];
    const float* fc2_b = (const float*)d_in[12];
    const float* fc3_w = (const float*)d_in[13];
    const float* fc3_b = (const float*)d_in[14];
    float* out = (float*)d_out;

    int B = in_sizes[0] / 24;
    actor_fused_kernel<<<B, 256, 0, stream>>>(
        state24, Wl1, Wr1, att1, b1, Wl2, Wr2, att2, b2,
        fc1_w, fc1_b, fc2_w, fc2_b, fc3_w, fc3_b, out, B);
}

// Round 5
// 134.156 us; speedup vs baseline: 2.2481x; 1.0184x over previous
//
#include <hip/hip_runtime.h>
#include <hip/hip_fp16.h>
#include <math.h>

#define PI_D 3.141592653589793

typedef _Float16 h2 __attribute__((ext_vector_type(2)));
typedef _Float16 h4 __attribute__((ext_vector_type(4)));
typedef _Float16 h8 __attribute__((ext_vector_type(8)));
typedef unsigned short us8 __attribute__((ext_vector_type(8)));
typedef __fp16 f16v2 __attribute__((ext_vector_type(2)));

#define STR1 264     // row stride in halves (528 B = 16B-aligned rows for b128)
#define STR1H 132    // in h2 units
#define STR1O 33     // in h8 units
#define STR2 66      // gl2/gr2 row stride in floats

static __device__ __forceinline__ h2 pack_h2(float a, float b) {
    return __builtin_bit_cast(h2, __builtin_amdgcn_cvt_pkrtz(a, b));
}

static __device__ __forceinline__ float fdot2(h2 a, h2 b, float c) {
    return __builtin_amdgcn_fdot2(__builtin_bit_cast(f16v2, a),
                                  __builtin_bit_cast(f16v2, b), c, false);
}

static __device__ __forceinline__ h8 habs8(h8 x) {
    us8 u = __builtin_bit_cast(us8, x);
    us8 m = {0x7fff, 0x7fff, 0x7fff, 0x7fff, 0x7fff, 0x7fff, 0x7fff, 0x7fff};
    return __builtin_bit_cast(h8, (us8)(u & m));
}

__global__ __launch_bounds__(256, 4) void actor_fused_kernel(
    const float* __restrict__ state24,
    const float* __restrict__ Wl1, const float* __restrict__ Wr1,
    const float* __restrict__ att1, const float* __restrict__ b1,
    const float* __restrict__ Wl2, const float* __restrict__ Wr2,
    const float* __restrict__ att2, const float* __restrict__ b2,
    const float* __restrict__ fc1_w, const float* __restrict__ fc1_b,
    const float* __restrict__ fc2_w, const float* __restrict__ fc2_b,
    const float* __restrict__ fc3_w, const float* __restrict__ fc3_b,
    float* __restrict__ out, int B)
{
    const int bix = blockIdx.x;
    if (bix >= B) return;
    const int tid = threadIdx.x;

    __shared__ float sinL[20], cosL[20], laserL[20], robotL[4];
    __shared__ __align__(16) h2 attLh[128];          // att1 fp16 pairs [h][32]
    __shared__ __align__(16) float att2L[64];
    __shared__ __align__(16) _Float16 gr1h[24 * STR1];   // r-transform, then h1 (21 + 3 zero rows)
    __shared__ __align__(16) union {
        struct { _Float16 gl1h[21 * STR1]; float eP[1764]; float uv[168]; } p1;
        struct { float gl2[24 * STR2]; float gr2[24 * STR2]; float e2[504];
                 float red[4][256]; float nfv[64]; float ha[256]; float hb[256]; } p2;
    } U;

    // ---- setup ----
    if (tid < 20) {
        double step = (PI_D + 0.03) / 20.0;
        float bound = (float)(-PI_D / 2.0 - 0.03 + (double)tid * step);
        float ang = bound + (float)(PI_D / 20.0);
        sinL[tid] = sinf(ang);
        cosL[tid] = cosf(ang);
        laserL[tid] = state24[bix * 24 + tid] * 0.1f;
    }
    if (tid >= 32 && tid < 36) robotL[tid - 32] = state24[bix * 24 + 20 + (tid - 32)];
    if (tid < 128) {
        float2 ap = ((const float2*)att1)[tid];
        attLh[tid] = pack_h2(ap.x, ap.y);
    }
    if (tid < 64) att2L[tid] = att2[tid];
    __syncthreads();

    // ---- layer-1 transforms -> fp16 LDS ----
    {
        float wl[7], wr[7];
        #pragma unroll
        for (int k = 0; k < 7; k++) { wl[k] = Wl1[k * 256 + tid]; wr[k] = Wr1[k * 256 + tid]; }
        #pragma unroll
        for (int n = 0; n < 20; n++) {
            float l = laserL[n], s = sinL[n], c = cosL[n];
            U.p1.gl1h[n * STR1 + tid] = (_Float16)(l * wl[0] + s * wl[1] + c * wl[2]);
            gr1h[n * STR1 + tid]     = (_Float16)(l * wr[0] + s * wr[1] + c * wr[2]);
        }
        float r0 = robotL[0], r1 = robotL[1], r2 = robotL[2], r3 = robotL[3];
        U.p1.gl1h[20 * STR1 + tid] = (_Float16)(r0 * wl[3] + r1 * wl[4] + r2 * wl[5] + r3 * wl[6]);
        gr1h[20 * STR1 + tid]     = (_Float16)(r0 * wr[3] + r1 * wr[4] + r2 * wr[5] + r3 * wr[6]);
    }
    __syncthreads();

    // ---- u/v precompute: uv[t<84] = att[h].gl1[j],  uv[84+..] = att[h].gr1[i] ----
    if (tid < 168) {
        int r = tid < 84 ? tid : tid - 84;
        int h = r / 21, idx = r - h * 21;
        const _Float16* rowp = (tid < 84 ? U.p1.gl1h : gr1h) + idx * STR1 + h * 64;
        const h8* row8 = (const h8*)rowp;
        const h2* ar = attLh + h * 32;
        float l0 = 0.f, l1 = 0.f;
        #pragma unroll
        for (int ch = 0; ch < 8; ++ch) {
            h8 g = row8[ch];
            l0 = fdot2(__builtin_shufflevector(g, g, 0, 1), ar[ch * 4 + 0], l0);
            l1 = fdot2(__builtin_shufflevector(g, g, 2, 3), ar[ch * 4 + 1], l1);
            l0 = fdot2(__builtin_shufflevector(g, g, 4, 5), ar[ch * 4 + 2], l0);
            l1 = fdot2(__builtin_shufflevector(g, g, 6, 7), ar[ch * 4 + 3], l1);
        }
        U.p1.uv[tid] = l0 + l1;
    }
    __syncthreads();

    // ---- layer-1 logits: abs part only (linear part factored into u/v) ----
    {
        const int h = tid >> 6;           // wave-uniform head
        const int lane = tid & 63;
        h2 ar[32];
        #pragma unroll
        for (int q = 0; q < 32; ++q) ar[q] = attLh[h * 32 + q];
        const float* uvU = U.p1.uv + h * 21;
        const float* uvV = U.p1.uv + 84 + h * 21;

        for (int it = 0; it < 7; ++it) {
            int q = it * 64 + lane;
            if (q < 441) {
                int i = q / 21;
                int j = q - i * 21;
                const h8* gA8 = (const h8*)(U.p1.gl1h + j * STR1 + h * 64);
                const h8* gB8 = (const h8*)(gr1h + i * STR1 + h * 64);
                float m0 = 0.f, m1 = 0.f;
                #pragma unroll
                for (int ch = 0; ch < 8; ++ch) {
                    h8 x = gA8[ch] + gB8[ch];
                    h8 ax = habs8(x);
                    m0 = fdot2(__builtin_shufflevector(ax, ax, 0, 1), ar[ch * 4 + 0], m0);
                    m1 = fdot2(__builtin_shufflevector(ax, ax, 2, 3), ar[ch * 4 + 1], m1);
                    m0 = fdot2(__builtin_shufflevector(ax, ax, 4, 5), ar[ch * 4 + 2], m0);
                    m1 = fdot2(__builtin_shufflevector(ax, ax, 6, 7), ar[ch * 4 + 3], m1);
                }
                U.p1.eP[h * 441 + q] = 0.6f * (uvU[j] + uvV[i]) + 0.4f * (m0 + m1);
            }
        }
    }
    __syncthreads();

    // ---- softmax over j + pre-normalize (84 rows) ----
    if (tid < 84) {
        float* row = U.p1.eP + tid * 21;
        float m = row[0];
        #pragma unroll
        for (int j = 1; j < 21; j++) m = fmaxf(m, row[j]);
        float s = 0.f;
        #pragma unroll
        for (int j = 0; j < 21; j++) { float v = __expf(row[j] - m); row[j] = v; s += v; }
        float r = 1.f / s;
        #pragma unroll
        for (int j = 0; j < 21; j++) row[j] *= r;
    }
    __syncthreads();

    // ---- layer-1 aggregation + bias + ELU -> h1 (fp16) + zero-pad rows 21..23 ----
    {
        h2 zz = {(_Float16)0.f, (_Float16)0.f};
        for (int z = tid; z < 384; z += 256)
            ((h2*)gr1h)[(21 + (z >> 7)) * STR1H + (z & 127)] = zz;

        int p = tid & 127, gi = tid >> 7;
        int h = p >> 5;
        float2 bb = ((const float2*)b1)[p];
        const h2* gcol = (const h2*)U.p1.gl1h + p;
        for (int i = gi; i < 21; i += 2) {
            const float* al = U.p1.eP + (h * 21 + i) * 21;
            float a0 = 0.f, a1 = 0.f;
            #pragma unroll
            for (int j = 0; j < 21; ++j) {
                float alpha = al[j];
                h2 gv = gcol[j * STR1H];
                a0 = fmaf(alpha, (float)gv.x, a0);
                a1 = fmaf(alpha, (float)gv.y, a1);
            }
            float v0 = a0 + bb.x, v1 = a1 + bb.y;
            v0 = v0 > 0.f ? v0 : __expf(v0) - 1.f;
            v1 = v1 > 0.f ? v1 : __expf(v1) - 1.f;
            h2 o; o.x = (_Float16)v0; o.y = (_Float16)v1;
            ((h2*)gr1h)[i * STR1H + p] = o;
        }
    }
    __syncthreads();

    // ---- layer-2 transforms via v_dot2_f32_f16, b128 h1 reads ----
    {
        int c = tid & 63, g = tid >> 6;
        float accL[6] = {0, 0, 0, 0, 0, 0}, accR[6] = {0, 0, 0, 0, 0, 0};
        const h8* hrow8 = (const h8*)gr1h;
        const float* pwl = Wl2 + c;
        const float* pwr = Wr2 + c;
        for (int ch = 0; ch < 32; ++ch) {
            float wlv[8], wrv[8];
            #pragma unroll
            for (int r = 0; r < 8; ++r) {
                wlv[r] = pwl[(8 * ch + r) * 64];
                wrv[r] = pwr[(8 * ch + r) * 64];
            }
            h2 wlA = pack_h2(wlv[0], wlv[1]), wlB = pack_h2(wlv[2], wlv[3]);
            h2 wlC = pack_h2(wlv[4], wlv[5]), wlD = pack_h2(wlv[6], wlv[7]);
            h2 wrA = pack_h2(wrv[0], wrv[1]), wrB = pack_h2(wrv[2], wrv[3]);
            h2 wrC = pack_h2(wrv[4], wrv[5]), wrD = pack_h2(wrv[6], wrv[7]);
            #pragma unroll
            for (int m = 0; m < 6; ++m) {
                int n = g + 4 * m;           // 0..23 uniform
                h8 hv = hrow8[n * STR1O + ch];
                h2 s0 = __builtin_shufflevector(hv, hv, 0, 1);
                h2 s1 = __builtin_shufflevector(hv, hv, 2, 3);
                h2 s2 = __builtin_shufflevector(hv, hv, 4, 5);
                h2 s3 = __builtin_shufflevector(hv, hv, 6, 7);
                accL[m] = fdot2(s0, wlA, accL[m]);
                accL[m] = fdot2(s1, wlB, accL[m]);
                accL[m] = fdot2(s2, wlC, accL[m]);
                accL[m] = fdot2(s3, wlD, accL[m]);
                accR[m] = fdot2(s0, wrA, accR[m]);
                accR[m] = fdot2(s1, wrB, accR[m]);
                accR[m] = fdot2(s2, wrC, accR[m]);
                accR[m] = fdot2(s3, wrD, accR[m]);
            }
        }
        #pragma unroll
        for (int m = 0; m < 6; ++m) {
            int n = g + 4 * m;
            U.p2.gl2[n * STR2 + c] = accL[m];
            U.p2.gr2[n * STR2 + c] = accR[m];
        }
    }
    __syncthreads();

    // ---- layer-2 logits (1 head), fp32 abs-trick ----
    for (int it = 0; it < 2; ++it) {
        int t = it * 256 + tid;
        if (t < 441) {
            int i = t / 21;
            int j = t - i * 21;
            const float2* gA = (const float2*)(U.p2.gl2 + j * STR2);
            const float2* gB = (const float2*)(U.p2.gr2 + i * STR2);
            const float2* aa = (const float2*)att2L;
            float l0 = 0.f, l1 = 0.f, m0 = 0.f, m1 = 0.f;
            #pragma unroll
            for (int dp = 0; dp < 32; ++dp) {
                float2 va = gA[dp], vb = gB[dp], a = aa[dp];
                float x0 = va.x + vb.x, x1 = va.y + vb.y;
                l0 = fmaf(a.x, x0, l0); m0 = fmaf(a.x, fabsf(x0), m0);
                l1 = fmaf(a.y, x1, l1); m1 = fmaf(a.y, fabsf(x1), m1);
            }
            U.p2.e2[t] = 0.6f * (l0 + l1) + 0.4f * (m0 + m1);
        }
    }
    __syncthreads();

    // ---- softmax-2 (21 rows) + zero rows 21..23 ----
    if (tid < 24) {
        float* row = U.p2.e2 + tid * 21;
        if (tid < 21) {
            float m = row[0];
            #pragma unroll
            for (int j = 1; j < 21; j++) m = fmaxf(m, row[j]);
            float s = 0.f;
            #pragma unroll
            for (int j = 0; j < 21; j++) { float v = __expf(row[j] - m); row[j] = v; s += v; }
            float r = 1.f / s;
            #pragma unroll
            for (int j = 0; j < 21; j++) row[j] *= r;
        } else {
            #pragma unroll
            for (int j = 0; j < 21; j++) row[j] = 0.f;
        }
    }
    __syncthreads();

    // ---- layer-2 aggregation + mean-pool partials ----
    {
        int d = tid & 63, g = tid >> 6;
        float sacc = 0.f;
        #pragma unroll
        for (int m = 0; m < 6; ++m) {
            int i = g + 4 * m;
            const float* al = U.p2.e2 + i * 21;
            float acc = 0.f;
            #pragma unroll
            for (int j = 0; j < 21; ++j) acc = fmaf(al[j], U.p2.gl2[j * STR2 + d], acc);
            sacc += acc;
        }
        U.p2.red[g][d] = sacc;
    }
    __syncthreads();
    if (tid < 64) {
        U.p2.nfv[tid] = (U.p2.red[0][tid] + U.p2.red[1][tid] + U.p2.red[2][tid] + U.p2.red[3][tid])
                        * (1.f / 21.f) + b2[tid];
    }
    __syncthreads();

    // ---- FC1 (64 -> 256): 4 outputs/thread via float4, k split over 4 groups ----
    {
        int c = tid & 63, g = tid >> 6;
        const float4* w4 = (const float4*)fc1_w;   // [k][64] float4s
        float4 acc = {0.f, 0.f, 0.f, 0.f};
        #pragma unroll
        for (int kk = 0; kk < 16; ++kk) {
            int k = g * 16 + kk;
            float xv = U.p2.nfv[k];
            float4 w = w4[k * 64 + c];
            acc.x = fmaf(xv, w.x, acc.x);
            acc.y = fmaf(xv, w.y, acc.y);
            acc.z = fmaf(xv, w.z, acc.z);
            acc.w = fmaf(xv, w.w, acc.w);
        }
        ((float4*)U.p2.red[g])[c] = acc;
    }
    __syncthreads();
    {
        float v = U.p2.red[0][tid] + U.p2.red[1][tid] + U.p2.red[2][tid] + U.p2.red[3][tid]
                  + fc1_b[tid];
        U.p2.ha[tid] = fmaxf(v, 0.f);
    }
    __syncthreads();

    // ---- FC2 (256 -> 256): 4 outputs/thread via float4, k split over 4 groups ----
    {
        int c = tid & 63, g = tid >> 6;
        const float4* w4 = (const float4*)fc2_w;
        float4 acc = {0.f, 0.f, 0.f, 0.f};
        #pragma unroll 8
        for (int kk = 0; kk < 64; ++kk) {
            int k = g * 64 + kk;
            float xv = U.p2.ha[k];
            float4 w = w4[k * 64 + c];
            acc.x = fmaf(xv, w.x, acc.x);
            acc.y = fmaf(xv, w.y, acc.y);
            acc.z = fmaf(xv, w.z, acc.z);
            acc.w = fmaf(xv, w.w, acc.w);
        }
        ((float4*)U.p2.red[g])[c] = acc;
    }
    __syncthreads();
    {
        float v = U.p2.red[0][tid] + U.p2.red[1][tid] + U.p2.red[2][tid] + U.p2.red[3][tid]
                  + fc2_b[tid];
        U.p2.hb[tid] = fmaxf(v, 0.f);
    }
    __syncthreads();

    // ---- FC3 (256 -> 2) + tanh ----
    if (tid < 128) {
        int o = tid >> 6, l = tid & 63;
        float s = 0.f;
        #pragma unroll
        for (int m = 0; m < 4; m++) { int k = l + 64 * m; s = fmaf(U.p2.hb[k], fc3_w[k * 2 + o], s); }
        #pragma unroll
        for (int off = 32; off >= 1; off >>= 1) s += __shfl_down(s, off, 64);
        if (l == 0) out[bix * 2 + o] = tanhf(s + fc3_b[o]);
    }
}

extern "C" void kernel_launch(void* const* d_in, const int* in_sizes, int n_in,
                              void* d_out, int out_size, void* d_ws, size_t ws_size,
                              hipStream_t stream) {
    const float* state24 = (const float*)d_in[0];
    const float* Wl1 = (const float*)d_in[1];
    const float* Wr1 = (const float*)d_in[2];
    const float* att1 = (const float*)d_in[3];
    const float* b1 = (const float*)d_in[4];
    const float* Wl2 = (const float*)d_in[5];
    const float* Wr2 = (const float*)d_in[6];
    const float* att2 = (const float*)d_in[7];
    const float* b2 = (const float*)d_in[8];
    const float* fc1_w = (const float*)d_in[9];
    const float* fc1_b = (const float*)d_in[10];
    const float* fc2_w = (const float*)d_in[11];
    const float* fc2_b = (const float*)d_in[12];
    const float* fc3_w = (const float*)d_in[13];
    const float* fc3_b = (const float*)d_in[14];
    float* out = (float*)d_out;

    int B = in_sizes[0] / 24;
    actor_fused_kernel<<<B, 256, 0, stream>>>(
        state24, Wl1, Wr1, att1, b1, Wl2, Wr2, att2, b2,
        fc1_w, fc1_b, fc2_w, fc2_b, fc3_w, fc3_b, out, B);
}

// Round 7
// 130.542 us; speedup vs baseline: 2.3103x; 1.0277x over previous
//
#include <hip/hip_runtime.h>
#include <hip/hip_fp16.h>
#include <math.h>

#define PI_D 3.141592653589793

typedef _Float16 h2 __attribute__((ext_vector_type(2)));
typedef _Float16 h8 __attribute__((ext_vector_type(8)));
typedef unsigned short us8 __attribute__((ext_vector_type(8)));
typedef __fp16 f16v2 __attribute__((ext_vector_type(2)));

#define STR1 264     // gl1h/gr1h row stride in halves (528 B, 16B-aligned rows)
#define STR1O 33     // in h8 units
#define STR2 66      // gl2/gr2 row stride in floats
#define EPS 24       // eP row stride in floats (96 B, 16B-aligned)

static __device__ __forceinline__ h2 pack_h2(float a, float b) {
    return __builtin_bit_cast(h2, __builtin_amdgcn_cvt_pkrtz(a, b));
}

static __device__ __forceinline__ float fdot2(h2 a, h2 b, float c) {
    return __builtin_amdgcn_fdot2(__builtin_bit_cast(f16v2, a),
                                  __builtin_bit_cast(f16v2, b), c, false);
}

static __device__ __forceinline__ h8 habs8(h8 x) {
    us8 u = __builtin_bit_cast(us8, x);
    us8 m = {0x7fff, 0x7fff, 0x7fff, 0x7fff, 0x7fff, 0x7fff, 0x7fff, 0x7fff};
    return __builtin_bit_cast(h8, (us8)(u & m));
}

// ---- pre-pass: pack weights to fp16 in consumption layout ----
// ws h8 segments: [0..2048) Wl2, [2048..4096) Wr2, [4096..6144) fc1, [6144..14336) fc2
__global__ __launch_bounds__(256) void pack_weights_kernel(
    const float* __restrict__ Wl2, const float* __restrict__ Wr2,
    const float* __restrict__ fc1_w, const float* __restrict__ fc2_w,
    h8* __restrict__ ws)
{
    int idx = blockIdx.x * 256 + threadIdx.x;
    if (idx < 4096) {
        const float* W = idx < 2048 ? Wl2 : Wr2;
        int t = idx & 2047;
        int ch = t >> 6, c = t & 63;
        h8 o;
        #pragma unroll
        for (int r = 0; r < 8; ++r) o[r] = (_Float16)W[(8 * ch + r) * 64 + c];
        ws[idx] = o;
    } else if (idx < 6144) {
        int t = idx - 4096;
        int k2 = t >> 6, c = t & 63;
        h8 o;
        #pragma unroll
        for (int q = 0; q < 4; ++q) {
            o[2 * q]     = (_Float16)fc1_w[(2 * k2) * 256 + 4 * c + q];
            o[2 * q + 1] = (_Float16)fc1_w[(2 * k2 + 1) * 256 + 4 * c + q];
        }
        ws[idx] = o;
    } else {
        int t = idx - 6144;
        int k2 = t >> 6, c = t & 63;
        h8 o;
        #pragma unroll
        for (int q = 0; q < 4; ++q) {
            o[2 * q]     = (_Float16)fc2_w[(2 * k2) * 256 + 4 * c + q];
            o[2 * q + 1] = (_Float16)fc2_w[(2 * k2 + 1) * 256 + 4 * c + q];
        }
        ws[idx] = o;
    }
}

__global__ __launch_bounds__(256, 4) void actor_fused_kernel(
    const float* __restrict__ state24,
    const float* __restrict__ Wl1, const float* __restrict__ Wr1,
    const float* __restrict__ att1, const float* __restrict__ b1,
    const float* __restrict__ att2, const float* __restrict__ b2,
    const float* __restrict__ fc1_b, const float* __restrict__ fc2_b,
    const float* __restrict__ fc3_w, const float* __restrict__ fc3_b,
    const h8* __restrict__ wsL, const h8* __restrict__ wsR,
    const h8* __restrict__ wsF1, const h8* __restrict__ wsF2,
    float* __restrict__ out, int B)
{
    const int bix = blockIdx.x;
    if (bix >= B) return;
    const int tid = threadIdx.x;

    __shared__ float sinL[20], cosL[20], laserL[20], robotL[4];
    __shared__ __align__(16) h2 attLh[128];          // att1 fp16 pairs [h][32]
    __shared__ __align__(16) float att2L[64];
    __shared__ __align__(16) _Float16 gr1h[24 * STR1];   // r-transform, then h1 (21 + 3 zero rows)
    __shared__ __align__(16) union {
        struct { _Float16 gl1h[21 * STR1];           // 11088 B
                 float eP[84 * EPS];                  // 8064 B, rows 96 B
                 float uv[168]; } p1;
        struct { float gl2[24 * STR2]; float gr2[24 * STR2]; float e2[504];
                 float red[4][256];
                 _Float16 nfvh[64]; _Float16 hah[256]; _Float16 hbh[256]; } p2;
    } U;

    // ---- setup ----
    if (tid < 20) {
        double step = (PI_D + 0.03) / 20.0;
        float bound = (float)(-PI_D / 2.0 - 0.03 + (double)tid * step);
        float ang = bound + (float)(PI_D / 20.0);
        sinL[tid] = sinf(ang);
        cosL[tid] = cosf(ang);
        laserL[tid] = state24[bix * 24 + tid] * 0.1f;
    }
    if (tid >= 32 && tid < 36) robotL[tid - 32] = state24[bix * 24 + 20 + (tid - 32)];
    if (tid < 128) {
        float2 ap = ((const float2*)att1)[tid];
        attLh[tid] = pack_h2(ap.x, ap.y);
    }
    if (tid < 64) att2L[tid] = att2[tid];
    __syncthreads();

    // ---- layer-1 transforms -> fp16 LDS ----
    {
        float wl[7], wr[7];
        #pragma unroll
        for (int k = 0; k < 7; k++) { wl[k] = Wl1[k * 256 + tid]; wr[k] = Wr1[k * 256 + tid]; }
        #pragma unroll
        for (int n = 0; n < 20; n++) {
            float l = laserL[n], s = sinL[n], c = cosL[n];
            U.p1.gl1h[n * STR1 + tid] = (_Float16)(l * wl[0] + s * wl[1] + c * wl[2]);
            gr1h[n * STR1 + tid]     = (_Float16)(l * wr[0] + s * wr[1] + c * wr[2]);
        }
        float r0 = robotL[0], r1 = robotL[1], r2 = robotL[2], r3 = robotL[3];
        U.p1.gl1h[20 * STR1 + tid] = (_Float16)(r0 * wl[3] + r1 * wl[4] + r2 * wl[5] + r3 * wl[6]);
        gr1h[20 * STR1 + tid]     = (_Float16)(r0 * wr[3] + r1 * wr[4] + r2 * wr[5] + r3 * wr[6]);
    }
    __syncthreads();

    // ---- u/v precompute: uv[t<84] = att[h].gl1[j],  uv[84+..] = att[h].gr1[i] ----
    if (tid < 168) {
        int r = tid < 84 ? tid : tid - 84;
        int h = r / 21, idx = r - h * 21;
        const _Float16* rowp = (tid < 84 ? U.p1.gl1h : gr1h) + idx * STR1 + h * 64;
        const h8* row8 = (const h8*)rowp;
        const h2* ar = attLh + h * 32;
        float l0 = 0.f, l1 = 0.f;
        #pragma unroll
        for (int ch = 0; ch < 8; ++ch) {
            h8 g = row8[ch];
            l0 = fdot2(__builtin_shufflevector(g, g, 0, 1), ar[ch * 4 + 0], l0);
            l1 = fdot2(__builtin_shufflevector(g, g, 2, 3), ar[ch * 4 + 1], l1);
            l0 = fdot2(__builtin_shufflevector(g, g, 4, 5), ar[ch * 4 + 2], l0);
            l1 = fdot2(__builtin_shufflevector(g, g, 6, 7), ar[ch * 4 + 3], l1);
        }
        U.p1.uv[tid] = l0 + l1;
    }
    __syncthreads();

    // ---- layer-1 logits: abs part only (linear part factored into u/v) ----
    {
        const int h = tid >> 6;           // wave-uniform head
        const int lane = tid & 63;
        h2 ar[32];
        #pragma unroll
        for (int q = 0; q < 32; ++q) ar[q] = attLh[h * 32 + q];
        const float* uvU = U.p1.uv + h * 21;
        const float* uvV = U.p1.uv + 84 + h * 21;

        for (int it = 0; it < 7; ++it) {
            int q = it * 64 + lane;
            if (q < 441) {
                int i = q / 21;
                int j = q - i * 21;
                const h8* gA8 = (const h8*)(U.p1.gl1h + j * STR1 + h * 64);
                const h8* gB8 = (const h8*)(gr1h + i * STR1 + h * 64);
                float m0 = 0.f, m1 = 0.f;
                #pragma unroll
                for (int ch = 0; ch < 8; ++ch) {
                    h8 x = gA8[ch] + gB8[ch];
                    h8 ax = habs8(x);
                    m0 = fdot2(__builtin_shufflevector(ax, ax, 0, 1), ar[ch * 4 + 0], m0);
                    m1 = fdot2(__builtin_shufflevector(ax, ax, 2, 3), ar[ch * 4 + 1], m1);
                    m0 = fdot2(__builtin_shufflevector(ax, ax, 4, 5), ar[ch * 4 + 2], m0);
                    m1 = fdot2(__builtin_shufflevector(ax, ax, 6, 7), ar[ch * 4 + 3], m1);
                }
                U.p1.eP[(h * 21 + i) * EPS + j] = 0.6f * (uvU[j] + uvV[i]) + 0.4f * (m0 + m1);
            }
        }
    }
    __syncthreads();

    // ---- softmax over j + pre-normalize (84 rows, stride EPS) ----
    if (tid < 84) {
        float* row = U.p1.eP + tid * EPS;
        float m = row[0];
        #pragma unroll
        for (int j = 1; j < 21; j++) m = fmaxf(m, row[j]);
        float s = 0.f;
        #pragma unroll
        for (int j = 0; j < 21; j++) { float v = __expf(row[j] - m); row[j] = v; s += v; }
        float r = 1.f / s;
        #pragma unroll
        for (int j = 0; j < 21; j++) row[j] *= r;
    }
    __syncthreads();

    // ---- layer-1 aggregation: thread = (head, channel); gl column in regs;
    //      alpha rows via lane-uniform b128 broadcast reads ----
    {
        const int h = tid >> 6, c = tid & 63;
        const int col = h * 64 + c;
        float glv[21];
        #pragma unroll
        for (int j = 0; j < 21; ++j) glv[j] = (float)U.p1.gl1h[j * STR1 + col];
        float bb = b1[col];
        gr1h[21 * STR1 + col] = (_Float16)0.f;
        gr1h[22 * STR1 + col] = (_Float16)0.f;
        gr1h[23 * STR1 + col] = (_Float16)0.f;
        for (int i = 0; i < 21; ++i) {
            const float4* ar4 = (const float4*)(U.p1.eP + (h * 21 + i) * EPS);
            float4 q0 = ar4[0], q1 = ar4[1], q2 = ar4[2], q3 = ar4[3], q4 = ar4[4];
            float a20 = U.p1.eP[(h * 21 + i) * EPS + 20];
            float acc;
            acc = q0.x * glv[0];
            acc = fmaf(q0.y, glv[1], acc);
            acc = fmaf(q0.z, glv[2], acc);
            acc = fmaf(q0.w, glv[3], acc);
            acc = fmaf(q1.x, glv[4], acc);
            acc = fmaf(q1.y, glv[5], acc);
            acc = fmaf(q1.z, glv[6], acc);
            acc = fmaf(q1.w, glv[7], acc);
            acc = fmaf(q2.x, glv[8], acc);
            acc = fmaf(q2.y, glv[9], acc);
            acc = fmaf(q2.z, glv[10], acc);
            acc = fmaf(q2.w, glv[11], acc);
            acc = fmaf(q3.x, glv[12], acc);
            acc = fmaf(q3.y, glv[13], acc);
            acc = fmaf(q3.z, glv[14], acc);
            acc = fmaf(q3.w, glv[15], acc);
            acc = fmaf(q4.x, glv[16], acc);
            acc = fmaf(q4.y, glv[17], acc);
            acc = fmaf(q4.z, glv[18], acc);
            acc = fmaf(q4.w, glv[19], acc);
            acc = fmaf(a20, glv[20], acc);
            float v = acc + bb;
            v = v > 0.f ? v : __expf(v) - 1.f;
            gr1h[i * STR1 + col] = (_Float16)v;
        }
    }
    __syncthreads();

    // ---- layer-2 transforms: packed fp16 weights from ws, b128 h1 reads ----
    {
        int c = tid & 63, g = tid >> 6;
        float accL[6] = {0, 0, 0, 0, 0, 0}, accR[6] = {0, 0, 0, 0, 0, 0};
        const h8* hrow8 = (const h8*)gr1h;
        for (int ch = 0; ch < 32; ++ch) {
            h8 wl = wsL[ch * 64 + c];
            h8 wr = wsR[ch * 64 + c];
            h2 wlA = __builtin_shufflevector(wl, wl, 0, 1);
            h2 wlB = __builtin_shufflevector(wl, wl, 2, 3);
            h2 wlC = __builtin_shufflevector(wl, wl, 4, 5);
            h2 wlD = __builtin_shufflevector(wl, wl, 6, 7);
            h2 wrA = __builtin_shufflevector(wr, wr, 0, 1);
            h2 wrB = __builtin_shufflevector(wr, wr, 2, 3);
            h2 wrC = __builtin_shufflevector(wr, wr, 4, 5);
            h2 wrD = __builtin_shufflevector(wr, wr, 6, 7);
            #pragma unroll
            for (int m = 0; m < 6; ++m) {
                int n = g + 4 * m;           // 0..23 uniform
                h8 hv = hrow8[n * STR1O + ch];
                h2 s0 = __builtin_shufflevector(hv, hv, 0, 1);
                h2 s1 = __builtin_shufflevector(hv, hv, 2, 3);
                h2 s2 = __builtin_shufflevector(hv, hv, 4, 5);
                h2 s3 = __builtin_shufflevector(hv, hv, 6, 7);
                accL[m] = fdot2(s0, wlA, accL[m]);
                accL[m] = fdot2(s1, wlB, accL[m]);
                accL[m] = fdot2(s2, wlC, accL[m]);
                accL[m] = fdot2(s3, wlD, accL[m]);
                accR[m] = fdot2(s0, wrA, accR[m]);
                accR[m] = fdot2(s1, wrB, accR[m]);
                accR[m] = fdot2(s2, wrC, accR[m]);
                accR[m] = fdot2(s3, wrD, accR[m]);
            }
        }
        #pragma unroll
        for (int m = 0; m < 6; ++m) {
            int n = g + 4 * m;
            U.p2.gl2[n * STR2 + c] = accL[m];
            U.p2.gr2[n * STR2 + c] = accR[m];
        }
    }
    __syncthreads();

    // ---- layer-2 logits (1 head), fp32 abs-trick ----
    for (int it = 0; it < 2; ++it) {
        int t = it * 256 + tid;
        if (t < 441) {
            int i = t / 21;
            int j = t - i * 21;
            const float2* gA = (const float2*)(U.p2.gl2 + j * STR2);
            const float2* gB = (const float2*)(U.p2.gr2 + i * STR2);
            const float2* aa = (const float2*)att2L;
            float l0 = 0.f, l1 = 0.f, m0 = 0.f, m1 = 0.f;
            #pragma unroll
            for (int dp = 0; dp < 32; ++dp) {
                float2 va = gA[dp], vb = gB[dp], a = aa[dp];
                float x0 = va.x + vb.x, x1 = va.y + vb.y;
                l0 = fmaf(a.x, x0, l0); m0 = fmaf(a.x, fabsf(x0), m0);
                l1 = fmaf(a.y, x1, l1); m1 = fmaf(a.y, fabsf(x1), m1);
            }
            U.p2.e2[t] = 0.6f * (l0 + l1) + 0.4f * (m0 + m1);
        }
    }
    __syncthreads();

    // ---- softmax-2 (21 rows) + zero rows 21..23 ----
    if (tid < 24) {
        float* row = U.p2.e2 + tid * 21;
        if (tid < 21) {
            float m = row[0];
            #pragma unroll
            for (int j = 1; j < 21; j++) m = fmaxf(m, row[j]);
            float s = 0.f;
            #pragma unroll
            for (int j = 0; j < 21; j++) { float v = __expf(row[j] - m); row[j] = v; s += v; }
            float r = 1.f / s;
            #pragma unroll
            for (int j = 0; j < 21; j++) row[j] *= r;
        } else {
            #pragma unroll
            for (int j = 0; j < 21; j++) row[j] = 0.f;
        }
    }
    __syncthreads();

    // ---- layer-2 aggregation + mean-pool partials ----
    {
        int d = tid & 63, g = tid >> 6;
        float sacc = 0.f;
        #pragma unroll
        for (int m = 0; m < 6; ++m) {
            int i = g + 4 * m;
            const float* al = U.p2.e2 + i * 21;
            float acc = 0.f;
            #pragma unroll
            for (int j = 0; j < 21; ++j) acc = fmaf(al[j], U.p2.gl2[j * STR2 + d], acc);
            sacc += acc;
        }
        U.p2.red[g][d] = sacc;
    }
    __syncthreads();
    if (tid < 64) {
        float v = (U.p2.red[0][tid] + U.p2.red[1][tid] + U.p2.red[2][tid] + U.p2.red[3][tid])
                  * (1.f / 21.f) + b2[tid];
        U.p2.nfvh[tid] = (_Float16)v;
    }
    __syncthreads();

    // ---- FC1 (64 -> 256): fp16 packed weights, 4 outputs/thread ----
    {
        int c = tid & 63, g = tid >> 6;
        const h2* x2p = (const h2*)U.p2.nfvh;
        float4 acc = {0.f, 0.f, 0.f, 0.f};
        #pragma unroll
        for (int kk = 0; kk < 8; ++kk) {
            int k2 = g * 8 + kk;
            h8 w = wsF1[k2 * 64 + c];
            h2 x2 = x2p[k2];
            acc.x = fdot2(__builtin_shufflevector(w, w, 0, 1), x2, acc.x);
            acc.y = fdot2(__builtin_shufflevector(w, w, 2, 3), x2, acc.y);
            acc.z = fdot2(__builtin_shufflevector(w, w, 4, 5), x2, acc.z);
            acc.w = fdot2(__builtin_shufflevector(w, w, 6, 7), x2, acc.w);
        }
        ((float4*)U.p2.red[g])[c] = acc;
    }
    __syncthreads();
    {
        float v = U.p2.red[0][tid] + U.p2.red[1][tid] + U.p2.red[2][tid] + U.p2.red[3][tid]
                  + fc1_b[tid];
        U.p2.hah[tid] = (_Float16)fmaxf(v, 0.f);
    }
    __syncthreads();

    // ---- FC2 (256 -> 256): fp16 packed weights + fp16 activations ----
    {
        int c = tid & 63, g = tid >> 6;
        const h8* haH = (const h8*)U.p2.hah;
        float4 acc = {0.f, 0.f, 0.f, 0.f};
#define FC2_STEP(q, p)                                                          \
        {                                                                       \
            int k2 = g * 32 + (q) * 4 + (p);                                    \
            h8 w = wsF2[k2 * 64 + c];                                           \
            h2 x2 = __builtin_shufflevector(xa, xa, 2 * (p), 2 * (p) + 1);      \
            acc.x = fdot2(__builtin_shufflevector(w, w, 0, 1), x2, acc.x);      \
            acc.y = fdot2(__builtin_shufflevector(w, w, 2, 3), x2, acc.y);      \
            acc.z = fdot2(__builtin_shufflevector(w, w, 4, 5), x2, acc.z);      \
            acc.w = fdot2(__builtin_shufflevector(w, w, 6, 7), x2, acc.w);      \
        }
        #pragma unroll
        for (int q = 0; q < 8; ++q) {
            h8 xa = haH[g * 8 + q];
            FC2_STEP(q, 0)
            FC2_STEP(q, 1)
            FC2_STEP(q, 2)
            FC2_STEP(q, 3)
        }
#undef FC2_STEP
        ((float4*)U.p2.red[g])[c] = acc;
    }
    __syncthreads();
    {
        float v = U.p2.red[0][tid] + U.p2.red[1][tid] + U.p2.red[2][tid] + U.p2.red[3][tid]
                  + fc2_b[tid];
        U.p2.hbh[tid] = (_Float16)fmaxf(v, 0.f);
    }
    __syncthreads();

    // ---- FC3 (256 -> 2) + tanh ----
    if (tid < 128) {
        int o = tid >> 6, l = tid & 63;
        float s = 0.f;
        #pragma unroll
        for (int m = 0; m < 4; m++) {
            int k = l + 64 * m;
            s = fmaf((float)U.p2.hbh[k], fc3_w[k * 2 + o], s);
        }
        #pragma unroll
        for (int off = 32; off >= 1; off >>= 1) s += __shfl_down(s, off, 64);
        if (l == 0) out[bix * 2 + o] = tanhf(s + fc3_b[o]);
    }
}

extern "C" void kernel_launch(void* const* d_in, const int* in_sizes, int n_in,
                              void* d_out, int out_size, void* d_ws, size_t ws_size,
                              hipStream_t stream) {
    const float* state24 = (const float*)d_in[0];
    const float* Wl1 = (const float*)d_in[1];
    const float* Wr1 = (const float*)d_in[2];
    const float* att1 = (const float*)d_in[3];
    const float* b1 = (const float*)d_in[4];
    const float* Wl2 = (const float*)d_in[5];
    const float* Wr2 = (const float*)d_in[6];
    const float* att2 = (const float*)d_in[7];
    const float* b2 = (const float*)d_in[8];
    const float* fc1_w = (const float*)d_in[9];
    const float* fc1_b = (const float*)d_in[10];
    const float* fc2_w = (const float*)d_in[11];
    const float* fc2_b = (const float*)d_in[12];
    const float* fc3_w = (const float*)d_in[13];
    const float* fc3_b = (const float*)d_in[14];
    float* out = (float*)d_out;

    h8* ws = (h8*)d_ws;                 // 14336 h8 = 224 KiB
    const h8* wsL = ws;
    const h8* wsR = ws + 2048;
    const h8* wsF1 = ws + 4096;
    const h8* wsF2 = ws + 6144;

    pack_weights_kernel<<<56, 256, 0, stream>>>(Wl2, Wr2, fc1_w, fc2_w, ws);

    int B = in_sizes[0] / 24;
    actor_fused_kernel<<<B, 256, 0, stream>>>(
        state24, Wl1, Wr1, att1, b1, att2, b2,
        fc1_b, fc2_b, fc3_w, fc3_b,
        wsL, wsR, wsF1, wsF2, out, B);
}

// Round 8
// 117.584 us; speedup vs baseline: 2.5650x; 1.1102x over previous
//
#include <hip/hip_runtime.h>
#include <hip/hip_fp16.h>
#include <math.h>

#define PI_D 3.141592653589793

typedef _Float16 h2 __attribute__((ext_vector_type(2)));
typedef _Float16 h8 __attribute__((ext_vector_type(8)));
typedef unsigned short us8 __attribute__((ext_vector_type(8)));
typedef __fp16 f16v2 __attribute__((ext_vector_type(2)));
typedef __fp16 f16v8 __attribute__((ext_vector_type(8)));
typedef float f32x4 __attribute__((ext_vector_type(4)));

#define STR1 264     // gl1h/gr1h row stride in halves (528 B, 16B-aligned rows)
#define STR2 66      // gl2/gr2 row stride in floats
#define EPS 24       // eP row stride in floats (96 B, 16B-aligned)

static __device__ __forceinline__ h2 pack_h2(float a, float b) {
    return __builtin_bit_cast(h2, __builtin_amdgcn_cvt_pkrtz(a, b));
}

static __device__ __forceinline__ float fdot2(h2 a, h2 b, float c) {
    return __builtin_amdgcn_fdot2(__builtin_bit_cast(f16v2, a),
                                  __builtin_bit_cast(f16v2, b), c, false);
}

static __device__ __forceinline__ h8 habs8(h8 x) {
    us8 u = __builtin_bit_cast(us8, x);
    us8 m = {0x7fff, 0x7fff, 0x7fff, 0x7fff, 0x7fff, 0x7fff, 0x7fff, 0x7fff};
    return __builtin_bit_cast(h8, (us8)(u & m));
}

static __device__ __forceinline__ f32x4 mfma16(h8 a, h8 b, f32x4 c) {
    return __builtin_amdgcn_mfma_f32_16x16x32_f16(
        __builtin_bit_cast(f16v8, a), __builtin_bit_cast(f16v8, b), c, 0, 0, 0);
}

// ---- pre-pass: pack weights to fp16 ----
// ws h8 segments: [0..2048) Wl2 (MFMA B-frag), [2048..4096) Wr2 (MFMA B-frag),
//                 [4096..6144) fc1, [6144..14336) fc2
// MFMA B-frag order: idx = ntile*512 + kchunk*64 + lane;
//   h8[j] = W[kchunk*32 + (lane>>4)*8 + j][ntile*16 + (lane&15)]
__global__ __launch_bounds__(256) void pack_weights_kernel(
    const float* __restrict__ Wl2, const float* __restrict__ Wr2,
    const float* __restrict__ fc1_w, const float* __restrict__ fc2_w,
    h8* __restrict__ ws)
{
    int idx = blockIdx.x * 256 + threadIdx.x;
    if (idx < 4096) {
        const float* W = idx < 2048 ? Wl2 : Wr2;
        int t = idx & 2047;
        int ntile = t >> 9, rem = t & 511;
        int kchunk = rem >> 6, lane = rem & 63;
        int n = ntile * 16 + (lane & 15);
        int k0 = kchunk * 32 + (lane >> 4) * 8;
        h8 o;
        #pragma unroll
        for (int j = 0; j < 8; ++j) o[j] = (_Float16)W[(k0 + j) * 64 + n];
        ws[idx] = o;
    } else if (idx < 6144) {
        int t = idx - 4096;
        int k2 = t >> 6, c = t & 63;
        h8 o;
        #pragma unroll
        for (int q = 0; q < 4; ++q) {
            o[2 * q]     = (_Float16)fc1_w[(2 * k2) * 256 + 4 * c + q];
            o[2 * q + 1] = (_Float16)fc1_w[(2 * k2 + 1) * 256 + 4 * c + q];
        }
        ws[idx] = o;
    } else {
        int t = idx - 6144;
        int k2 = t >> 6, c = t & 63;
        h8 o;
        #pragma unroll
        for (int q = 0; q < 4; ++q) {
            o[2 * q]     = (_Float16)fc2_w[(2 * k2) * 256 + 4 * c + q];
            o[2 * q + 1] = (_Float16)fc2_w[(2 * k2 + 1) * 256 + 4 * c + q];
        }
        ws[idx] = o;
    }
}

__global__ __launch_bounds__(256, 4) void actor_fused_kernel(
    const float* __restrict__ state24,
    const float* __restrict__ Wl1, const float* __restrict__ Wr1,
    const float* __restrict__ att1, const float* __restrict__ b1,
    const float* __restrict__ att2, const float* __restrict__ b2,
    const float* __restrict__ fc1_b, const float* __restrict__ fc2_b,
    const float* __restrict__ fc3_w, const float* __restrict__ fc3_b,
    const h8* __restrict__ wsL, const h8* __restrict__ wsR,
    const h8* __restrict__ wsF1, const h8* __restrict__ wsF2,
    float* __restrict__ out, int B)
{
    const int bix = blockIdx.x;
    if (bix >= B) return;
    const int tid = threadIdx.x;

    __shared__ float sinL[20], cosL[20], laserL[20], robotL[4];
    __shared__ __align__(16) h2 attLh[128];          // att1 fp16 pairs [h][32]
    __shared__ __align__(16) float att2L[64];
    __shared__ __align__(16) _Float16 gr1h[32 * STR1];   // r-transform, then h1 (21 + 11 zero rows)
    __shared__ __align__(16) union {
        struct { _Float16 gl1h[21 * STR1];           // 11088 B
                 float eP[84 * EPS];                  // 8064 B
                 float uv[168]; } p1;
        struct { float gl2[24 * STR2]; float gr2[24 * STR2]; float e2[504];
                 float red[4][256];
                 _Float16 nfvh[64]; _Float16 hah[256]; _Float16 hbh[256]; } p2;
    } U;

    // ---- setup ----
    if (tid < 20) {
        double step = (PI_D + 0.03) / 20.0;
        float bound = (float)(-PI_D / 2.0 - 0.03 + (double)tid * step);
        float ang = bound + (float)(PI_D / 20.0);
        sinL[tid] = sinf(ang);
        cosL[tid] = cosf(ang);
        laserL[tid] = state24[bix * 24 + tid] * 0.1f;
    }
    if (tid >= 32 && tid < 36) robotL[tid - 32] = state24[bix * 24 + 20 + (tid - 32)];
    if (tid < 128) {
        float2 ap = ((const float2*)att1)[tid];
        attLh[tid] = pack_h2(ap.x, ap.y);
    }
    if (tid < 64) att2L[tid] = att2[tid];
    __syncthreads();

    // ---- layer-1 transforms -> fp16 LDS ----
    {
        float wl[7], wr[7];
        #pragma unroll
        for (int k = 0; k < 7; k++) { wl[k] = Wl1[k * 256 + tid]; wr[k] = Wr1[k * 256 + tid]; }
        #pragma unroll
        for (int n = 0; n < 20; n++) {
            float l = laserL[n], s = sinL[n], c = cosL[n];
            U.p1.gl1h[n * STR1 + tid] = (_Float16)(l * wl[0] + s * wl[1] + c * wl[2]);
            gr1h[n * STR1 + tid]     = (_Float16)(l * wr[0] + s * wr[1] + c * wr[2]);
        }
        float r0 = robotL[0], r1 = robotL[1], r2 = robotL[2], r3 = robotL[3];
        U.p1.gl1h[20 * STR1 + tid] = (_Float16)(r0 * wl[3] + r1 * wl[4] + r2 * wl[5] + r3 * wl[6]);
        gr1h[20 * STR1 + tid]     = (_Float16)(r0 * wr[3] + r1 * wr[4] + r2 * wr[5] + r3 * wr[6]);
    }
    __syncthreads();

    // ---- u/v precompute ----
    if (tid < 168) {
        int r = tid < 84 ? tid : tid - 84;
        int h = r / 21, idx = r - h * 21;
        const _Float16* rowp = (tid < 84 ? U.p1.gl1h : gr1h) + idx * STR1 + h * 64;
        const h8* row8 = (const h8*)rowp;
        const h2* ar = attLh + h * 32;
        float l0 = 0.f, l1 = 0.f;
        #pragma unroll
        for (int ch = 0; ch < 8; ++ch) {
            h8 g = row8[ch];
            l0 = fdot2(__builtin_shufflevector(g, g, 0, 1), ar[ch * 4 + 0], l0);
            l1 = fdot2(__builtin_shufflevector(g, g, 2, 3), ar[ch * 4 + 1], l1);
            l0 = fdot2(__builtin_shufflevector(g, g, 4, 5), ar[ch * 4 + 2], l0);
            l1 = fdot2(__builtin_shufflevector(g, g, 6, 7), ar[ch * 4 + 3], l1);
        }
        U.p1.uv[tid] = l0 + l1;
    }
    __syncthreads();

    // ---- layer-1 logits: abs part only ----
    {
        const int h = tid >> 6;
        const int lane = tid & 63;
        h2 ar[32];
        #pragma unroll
        for (int q = 0; q < 32; ++q) ar[q] = attLh[h * 32 + q];
        const float* uvU = U.p1.uv + h * 21;
        const float* uvV = U.p1.uv + 84 + h * 21;

        for (int it = 0; it < 7; ++it) {
            int q = it * 64 + lane;
            if (q < 441) {
                int i = q / 21;
                int j = q - i * 21;
                const h8* gA8 = (const h8*)(U.p1.gl1h + j * STR1 + h * 64);
                const h8* gB8 = (const h8*)(gr1h + i * STR1 + h * 64);
                float m0 = 0.f, m1 = 0.f;
                #pragma unroll
                for (int ch = 0; ch < 8; ++ch) {
                    h8 x = gA8[ch] + gB8[ch];
                    h8 ax = habs8(x);
                    m0 = fdot2(__builtin_shufflevector(ax, ax, 0, 1), ar[ch * 4 + 0], m0);
                    m1 = fdot2(__builtin_shufflevector(ax, ax, 2, 3), ar[ch * 4 + 1], m1);
                    m0 = fdot2(__builtin_shufflevector(ax, ax, 4, 5), ar[ch * 4 + 2], m0);
                    m1 = fdot2(__builtin_shufflevector(ax, ax, 6, 7), ar[ch * 4 + 3], m1);
                }
                U.p1.eP[(h * 21 + i) * EPS + j] = 0.6f * (uvU[j] + uvV[i]) + 0.4f * (m0 + m1);
            }
        }
    }
    __syncthreads();

    // ---- softmax over j + pre-normalize (84 rows) ----
    if (tid < 84) {
        float* row = U.p1.eP + tid * EPS;
        float m = row[0];
        #pragma unroll
        for (int j = 1; j < 21; j++) m = fmaxf(m, row[j]);
        float s = 0.f;
        #pragma unroll
        for (int j = 0; j < 21; j++) { float v = __expf(row[j] - m); row[j] = v; s += v; }
        float r = 1.f / s;
        #pragma unroll
        for (int j = 0; j < 21; j++) row[j] *= r;
    }
    __syncthreads();

    // ---- layer-1 aggregation + zero-pad h1 rows 21..31 ----
    {
        // zero rows 21..31 (row starts are h8-aligned: STR1*2 = 528 B)
        h8* z8 = (h8*)gr1h;
        h8 zz = {(_Float16)0.f, (_Float16)0.f, (_Float16)0.f, (_Float16)0.f,
                 (_Float16)0.f, (_Float16)0.f, (_Float16)0.f, (_Float16)0.f};
        for (int z = tid; z < 363; z += 256) z8[693 + z] = zz;   // 21*33=693, 11 rows * 33 h8

        const int h = tid >> 6, c = tid & 63;
        const int col = h * 64 + c;
        float glv[21];
        #pragma unroll
        for (int j = 0; j < 21; ++j) glv[j] = (float)U.p1.gl1h[j * STR1 + col];
        float bb = b1[col];
        for (int i = 0; i < 21; ++i) {
            const float4* ar4 = (const float4*)(U.p1.eP + (h * 21 + i) * EPS);
            float4 q0 = ar4[0], q1 = ar4[1], q2 = ar4[2], q3 = ar4[3], q4 = ar4[4];
            float a20 = U.p1.eP[(h * 21 + i) * EPS + 20];
            float acc;
            acc = q0.x * glv[0];
            acc = fmaf(q0.y, glv[1], acc);
            acc = fmaf(q0.z, glv[2], acc);
            acc = fmaf(q0.w, glv[3], acc);
            acc = fmaf(q1.x, glv[4], acc);
            acc = fmaf(q1.y, glv[5], acc);
            acc = fmaf(q1.z, glv[6], acc);
            acc = fmaf(q1.w, glv[7], acc);
            acc = fmaf(q2.x, glv[8], acc);
            acc = fmaf(q2.y, glv[9], acc);
            acc = fmaf(q2.z, glv[10], acc);
            acc = fmaf(q2.w, glv[11], acc);
            acc = fmaf(q3.x, glv[12], acc);
            acc = fmaf(q3.y, glv[13], acc);
            acc = fmaf(q3.z, glv[14], acc);
            acc = fmaf(q3.w, glv[15], acc);
            acc = fmaf(q4.x, glv[16], acc);
            acc = fmaf(q4.y, glv[17], acc);
            acc = fmaf(q4.z, glv[18], acc);
            acc = fmaf(q4.w, glv[19], acc);
            acc = fmaf(a20, glv[20], acc);
            float v = acc + bb;
            v = v > 0.f ? v : __expf(v) - 1.f;
            gr1h[i * STR1 + col] = (_Float16)v;
        }
    }
    __syncthreads();

    // ---- layer-2 transforms via MFMA 16x16x32 f16 ----
    // D[m=node][n=out] = sum_k h1[m][k] * W[k][n]; wave w handles ntile=w,
    // both matrices (L,R) and both M-tiles (nodes 0-15, 16-31; rows >=21 zero).
    {
        const int lane = tid & 63;
        const int w = tid >> 6;
        const int mrow = lane & 15;
        const int quad = lane >> 4;
        const h8* hA0 = (const h8*)(gr1h + mrow * STR1 + quad * 8);
        const h8* hA1 = (const h8*)(gr1h + (16 + mrow) * STR1 + quad * 8);
        const h8* bL = wsL + w * 512 + lane;
        const h8* bR = wsR + w * 512 + lane;
        f32x4 aL0 = {0.f, 0.f, 0.f, 0.f}, aL1 = {0.f, 0.f, 0.f, 0.f};
        f32x4 aR0 = {0.f, 0.f, 0.f, 0.f}, aR1 = {0.f, 0.f, 0.f, 0.f};
        #pragma unroll
        for (int kc = 0; kc < 8; ++kc) {
            h8 A0 = hA0[kc * 4];      // + kc*32 halves
            h8 A1 = hA1[kc * 4];
            h8 BL = bL[kc * 64];
            h8 BR = bR[kc * 64];
            aL0 = mfma16(A0, BL, aL0);
            aL1 = mfma16(A1, BL, aL1);
            aR0 = mfma16(A0, BR, aR0);
            aR1 = mfma16(A1, BR, aR1);
        }
        const int col = w * 16 + mrow;
        #pragma unroll
        for (int r = 0; r < 4; ++r) {
            int row0 = quad * 4 + r;
            U.p2.gl2[row0 * STR2 + col] = aL0[r];
            U.p2.gr2[row0 * STR2 + col] = aR0[r];
            int row1 = 16 + row0;
            if (row1 < 24) {
                U.p2.gl2[row1 * STR2 + col] = aL1[r];
                U.p2.gr2[row1 * STR2 + col] = aR1[r];
            }
        }
    }
    __syncthreads();

    // ---- layer-2 logits (1 head), fp32 abs-trick ----
    for (int it = 0; it < 2; ++it) {
        int t = it * 256 + tid;
        if (t < 441) {
            int i = t / 21;
            int j = t - i * 21;
            const float2* gA = (const float2*)(U.p2.gl2 + j * STR2);
            const float2* gB = (const float2*)(U.p2.gr2 + i * STR2);
            const float2* aa = (const float2*)att2L;
            float l0 = 0.f, l1 = 0.f, m0 = 0.f, m1 = 0.f;
            #pragma unroll
            for (int dp = 0; dp < 32; ++dp) {
                float2 va = gA[dp], vb = gB[dp], a = aa[dp];
                float x0 = va.x + vb.x, x1 = va.y + vb.y;
                l0 = fmaf(a.x, x0, l0); m0 = fmaf(a.x, fabsf(x0), m0);
                l1 = fmaf(a.y, x1, l1); m1 = fmaf(a.y, fabsf(x1), m1);
            }
            U.p2.e2[t] = 0.6f * (l0 + l1) + 0.4f * (m0 + m1);
        }
    }
    __syncthreads();

    // ---- softmax-2 (21 rows) + zero rows 21..23 ----
    if (tid < 24) {
        float* row = U.p2.e2 + tid * 21;
        if (tid < 21) {
            float m = row[0];
            #pragma unroll
            for (int j = 1; j < 21; j++) m = fmaxf(m, row[j]);
            float s = 0.f;
            #pragma unroll
            for (int j = 0; j < 21; j++) { float v = __expf(row[j] - m); row[j] = v; s += v; }
            float r = 1.f / s;
            #pragma unroll
            for (int j = 0; j < 21; j++) row[j] *= r;
        } else {
            #pragma unroll
            for (int j = 0; j < 21; j++) row[j] = 0.f;
        }
    }
    __syncthreads();

    // ---- layer-2 aggregation + mean-pool partials ----
    {
        int d = tid & 63, g = tid >> 6;
        float sacc = 0.f;
        #pragma unroll
        for (int m = 0; m < 6; ++m) {
            int i = g + 4 * m;
            const float* al = U.p2.e2 + i * 21;
            float acc = 0.f;
            #pragma unroll
            for (int j = 0; j < 21; ++j) acc = fmaf(al[j], U.p2.gl2[j * STR2 + d], acc);
            sacc += acc;
        }
        U.p2.red[g][d] = sacc;
    }
    __syncthreads();
    if (tid < 64) {
        float v = (U.p2.red[0][tid] + U.p2.red[1][tid] + U.p2.red[2][tid] + U.p2.red[3][tid])
                  * (1.f / 21.f) + b2[tid];
        U.p2.nfvh[tid] = (_Float16)v;
    }
    __syncthreads();

    // ---- FC1 (64 -> 256): fp16 packed weights ----
    {
        int c = tid & 63, g = tid >> 6;
        const h2* x2p = (const h2*)U.p2.nfvh;
        float4 acc = {0.f, 0.f, 0.f, 0.f};
        #pragma unroll
        for (int kk = 0; kk < 8; ++kk) {
            int k2 = g * 8 + kk;
            h8 w = wsF1[k2 * 64 + c];
            h2 x2 = x2p[k2];
            acc.x = fdot2(__builtin_shufflevector(w, w, 0, 1), x2, acc.x);
            acc.y = fdot2(__builtin_shufflevector(w, w, 2, 3), x2, acc.y);
            acc.z = fdot2(__builtin_shufflevector(w, w, 4, 5), x2, acc.z);
            acc.w = fdot2(__builtin_shufflevector(w, w, 6, 7), x2, acc.w);
        }
        ((float4*)U.p2.red[g])[c] = acc;
    }
    __syncthreads();
    {
        float v = U.p2.red[0][tid] + U.p2.red[1][tid] + U.p2.red[2][tid] + U.p2.red[3][tid]
                  + fc1_b[tid];
        U.p2.hah[tid] = (_Float16)fmaxf(v, 0.f);
    }
    __syncthreads();

    // ---- FC2 (256 -> 256): fp16 packed weights + fp16 activations ----
    {
        int c = tid & 63, g = tid >> 6;
        const h8* haH = (const h8*)U.p2.hah;
        float4 acc = {0.f, 0.f, 0.f, 0.f};
#define FC2_STEP(q, p)                                                          \
        {                                                                       \
            int k2 = g * 32 + (q) * 4 + (p);                                    \
            h8 w = wsF2[k2 * 64 + c];                                           \
            h2 x2 = __builtin_shufflevector(xa, xa, 2 * (p), 2 * (p) + 1);      \
            acc.x = fdot2(__builtin_shufflevector(w, w, 0, 1), x2, acc.x);      \
            acc.y = fdot2(__builtin_shufflevector(w, w, 2, 3), x2, acc.y);      \
            acc.z = fdot2(__builtin_shufflevector(w, w, 4, 5), x2, acc.z);      \
            acc.w = fdot2(__builtin_shufflevector(w, w, 6, 7), x2, acc.w);      \
        }
        #pragma unroll
        for (int q = 0; q < 8; ++q) {
            h8 xa = haH[g * 8 + q];
            FC2_STEP(q, 0)
            FC2_STEP(q, 1)
            FC2_STEP(q, 2)
            FC2_STEP(q, 3)
        }
#undef FC2_STEP
        ((float4*)U.p2.red[g])[c] = acc;
    }
    __syncthreads();
    {
        float v = U.p2.red[0][tid] + U.p2.red[1][tid] + U.p2.red[2][tid] + U.p2.red[3][tid]
                  + fc2_b[tid];
        U.p2.hbh[tid] = (_Float16)fmaxf(v, 0.f);
    }
    __syncthreads();

    // ---- FC3 (256 -> 2) + tanh ----
    if (tid < 128) {
        int o = tid >> 6, l = tid & 63;
        float s = 0.f;
        #pragma unroll
        for (int m = 0; m < 4; m++) {
            int k = l + 64 * m;
            s = fmaf((float)U.p2.hbh[k], fc3_w[k * 2 + o], s);
        }
        #pragma unroll
        for (int off = 32; off >= 1; off >>= 1) s += __shfl_down(s, off, 64);
        if (l == 0) out[bix * 2 + o] = tanhf(s + fc3_b[o]);
    }
}

extern "C" void kernel_launch(void* const* d_in, const int* in_sizes, int n_in,
                              void* d_out, int out_size, void* d_ws, size_t ws_size,
                              hipStream_t stream) {
    const float* state24 = (const float*)d_in[0];
    const float* Wl1 = (const float*)d_in[1];
    const float* Wr1 = (const float*)d_in[2];
    const float* att1 = (const float*)d_in[3];
    const float* b1 = (const float*)d_in[4];
    const float* Wl2 = (const float*)d_in[5];
    const float* Wr2 = (const float*)d_in[6];
    const float* att2 = (const float*)d_in[7];
    const float* b2 = (const float*)d_in[8];
    const float* fc1_w = (const float*)d_in[9];
    const float* fc1_b = (const float*)d_in[10];
    const float* fc2_w = (const float*)d_in[11];
    const float* fc2_b = (const float*)d_in[12];
    const float* fc3_w = (const float*)d_in[13];
    const float* fc3_b = (const float*)d_in[14];
    float* out = (float*)d_out;

    h8* ws = (h8*)d_ws;                 // 14336 h8 = 224 KiB
    const h8* wsL = ws;
    const h8* wsR = ws + 2048;
    const h8* wsF1 = ws + 4096;
    const h8* wsF2 = ws + 6144;

    pack_weights_kernel<<<56, 256, 0, stream>>>(Wl2, Wr2, fc1_w, fc2_w, ws);

    int B = in_sizes[0] / 24;
    actor_fused_kernel<<<B, 256, 0, stream>>>(
        state24, Wl1, Wr1, att1, b1, att2, b2,
        fc1_b, fc2_b, fc3_w, fc3_b,
        wsL, wsR, wsF1, wsF2, out, B);
}

// Round 9
// 115.345 us; speedup vs baseline: 2.6147x; 1.0194x over previous
//
#include <hip/hip_runtime.h>
#include <hip/hip_fp16.h>
#include <math.h>

#define PI_D 3.141592653589793

typedef _Float16 h2 __attribute__((ext_vector_type(2)));
typedef _Float16 h8 __attribute__((ext_vector_type(8)));
typedef unsigned short us8 __attribute__((ext_vector_type(8)));
typedef __fp16 f16v2 __attribute__((ext_vector_type(2)));
typedef __fp16 f16v8 __attribute__((ext_vector_type(8)));
typedef float f32x4 __attribute__((ext_vector_type(4)));

#define STR1 264     // gl1h/gr1h row stride in halves (528 B, 16B-aligned rows)
#define STR2 66      // gl2 fp32 row stride in floats
#define STR2H 72     // gl2h/gr2h fp16 row stride in halves (144 B, 16B-aligned)
#define EPS 24       // eP row stride in floats
#define EPS2 24      // e2 row stride in floats

static __device__ __forceinline__ h2 pack_h2(float a, float b) {
    return __builtin_bit_cast(h2, __builtin_amdgcn_cvt_pkrtz(a, b));
}

static __device__ __forceinline__ float fdot2(h2 a, h2 b, float c) {
    return __builtin_amdgcn_fdot2(__builtin_bit_cast(f16v2, a),
                                  __builtin_bit_cast(f16v2, b), c, false);
}

static __device__ __forceinline__ h8 habs8(h8 x) {
    us8 u = __builtin_bit_cast(us8, x);
    us8 m = {0x7fff, 0x7fff, 0x7fff, 0x7fff, 0x7fff, 0x7fff, 0x7fff, 0x7fff};
    return __builtin_bit_cast(h8, (us8)(u & m));
}

static __device__ __forceinline__ f32x4 mfma16(h8 a, h8 b, f32x4 c) {
    return __builtin_amdgcn_mfma_f32_16x16x32_f16(
        __builtin_bit_cast(f16v8, a), __builtin_bit_cast(f16v8, b), c, 0, 0, 0);
}

// ---- pre-pass: pack weights to fp16 ----
// ws h8 segments: [0..2048) Wl2 (MFMA B-frag), [2048..4096) Wr2 (MFMA B-frag),
//                 [4096..6144) fc1, [6144..14336) fc2
__global__ __launch_bounds__(256) void pack_weights_kernel(
    const float* __restrict__ Wl2, const float* __restrict__ Wr2,
    const float* __restrict__ fc1_w, const float* __restrict__ fc2_w,
    h8* __restrict__ ws)
{
    int idx = blockIdx.x * 256 + threadIdx.x;
    if (idx < 4096) {
        const float* W = idx < 2048 ? Wl2 : Wr2;
        int t = idx & 2047;
        int ntile = t >> 9, rem = t & 511;
        int kchunk = rem >> 6, lane = rem & 63;
        int n = ntile * 16 + (lane & 15);
        int k0 = kchunk * 32 + (lane >> 4) * 8;
        h8 o;
        #pragma unroll
        for (int j = 0; j < 8; ++j) o[j] = (_Float16)W[(k0 + j) * 64 + n];
        ws[idx] = o;
    } else if (idx < 6144) {
        int t = idx - 4096;
        int k2 = t >> 6, c = t & 63;
        h8 o;
        #pragma unroll
        for (int q = 0; q < 4; ++q) {
            o[2 * q]     = (_Float16)fc1_w[(2 * k2) * 256 + 4 * c + q];
            o[2 * q + 1] = (_Float16)fc1_w[(2 * k2 + 1) * 256 + 4 * c + q];
        }
        ws[idx] = o;
    } else {
        int t = idx - 6144;
        int k2 = t >> 6, c = t & 63;
        h8 o;
        #pragma unroll
        for (int q = 0; q < 4; ++q) {
            o[2 * q]     = (_Float16)fc2_w[(2 * k2) * 256 + 4 * c + q];
            o[2 * q + 1] = (_Float16)fc2_w[(2 * k2 + 1) * 256 + 4 * c + q];
        }
        ws[idx] = o;
    }
}

__global__ __launch_bounds__(256, 4) void actor_fused_kernel(
    const float* __restrict__ state24,
    const float* __restrict__ Wl1, const float* __restrict__ Wr1,
    const float* __restrict__ att1, const float* __restrict__ b1,
    const float* __restrict__ att2, const float* __restrict__ b2,
    const float* __restrict__ fc1_b, const float* __restrict__ fc2_b,
    const float* __restrict__ fc3_w, const float* __restrict__ fc3_b,
    const h8* __restrict__ wsL, const h8* __restrict__ wsR,
    const h8* __restrict__ wsF1, const h8* __restrict__ wsF2,
    float* __restrict__ out, int B)
{
    const int bix = blockIdx.x;
    if (bix >= B) return;
    const int tid = threadIdx.x;

    __shared__ float sinL[20], cosL[20], laserL[20], robotL[4];
    __shared__ __align__(16) h2 attLh[128];      // 0.4*att1 fp16 pairs [h][32]
    __shared__ __align__(16) h2 att2Lh[32];      // 0.4*att2 fp16 pairs
    __shared__ __align__(16) _Float16 gr1h[22 * STR1];   // r-transform, then h1 (21 rows + zero row 21)
    __shared__ __align__(16) union {
        struct { _Float16 gl1h[21 * STR1];            // 11088 B
                 float eP[84 * EPS];                   // 8064 B
                 float uv[168]; } p1;
        struct { float gl2[24 * STR2];                // fp32, output path (agg2)
                 _Float16 gl2h[24 * STR2H];           // fp16 mirrors, logit path
                 _Float16 gr2h[24 * STR2H];
                 float e2[24 * EPS2];
                 float u2v2[42];
                 float red[4][256];
                 _Float16 nfvh[64]; _Float16 hah[256]; _Float16 hbh[256]; } p2;
    } U;

    // ---- setup ----
    if (tid < 20) {
        double step = (PI_D + 0.03) / 20.0;
        float bound = (float)(-PI_D / 2.0 - 0.03 + (double)tid * step);
        float ang = bound + (float)(PI_D / 20.0);
        sinL[tid] = sinf(ang);
        cosL[tid] = cosf(ang);
        laserL[tid] = state24[bix * 24 + tid] * 0.1f;
    }
    if (tid >= 32 && tid < 36) robotL[tid - 32] = state24[bix * 24 + 20 + (tid - 32)];
    if (tid < 128) {
        float2 ap = ((const float2*)att1)[tid];
        attLh[tid] = pack_h2(0.4f * ap.x, 0.4f * ap.y);
    }
    if (tid >= 128 && tid < 160) {
        float2 ap = ((const float2*)att2)[tid - 128];
        att2Lh[tid - 128] = pack_h2(0.4f * ap.x, 0.4f * ap.y);
    }
    __syncthreads();

    // ---- layer-1 transforms -> fp16 LDS (h2 writes, 2 cols x ~11 nodes per thread) ----
    {
        const int d2 = tid & 127;      // handles dims 2*d2, 2*d2+1
        const int half = tid >> 7;     // wave-uniform: 0 -> nodes 0..10, 1 -> nodes 11..20
        float2 wl[7], wr[7];
        #pragma unroll
        for (int k = 0; k < 7; k++) {
            wl[k] = ((const float2*)Wl1)[k * 128 + d2];
            wr[k] = ((const float2*)Wr1)[k * 128 + d2];
        }
        const int base = half * 11;
        #pragma unroll
        for (int nn = 0; nn < 11; ++nn) {
            int node = base + nn;
            if (node < 21) {
                float a0, a1, b0, b1v;
                if (node < 20) {
                    float l = laserL[node], s = sinL[node], c = cosL[node];
                    a0 = l * wl[0].x + s * wl[1].x + c * wl[2].x;
                    a1 = l * wl[0].y + s * wl[1].y + c * wl[2].y;
                    b0 = l * wr[0].x + s * wr[1].x + c * wr[2].x;
                    b1v = l * wr[0].y + s * wr[1].y + c * wr[2].y;
                } else {
                    float r0 = robotL[0], r1 = robotL[1], r2 = robotL[2], r3 = robotL[3];
                    a0 = r0 * wl[3].x + r1 * wl[4].x + r2 * wl[5].x + r3 * wl[6].x;
                    a1 = r0 * wl[3].y + r1 * wl[4].y + r2 * wl[5].y + r3 * wl[6].y;
                    b0 = r0 * wr[3].x + r1 * wr[4].x + r2 * wr[5].x + r3 * wr[6].x;
                    b1v = r0 * wr[3].y + r1 * wr[4].y + r2 * wr[5].y + r3 * wr[6].y;
                }
                ((h2*)(U.p1.gl1h + node * STR1))[d2] = pack_h2(a0, a1);
                ((h2*)(gr1h + node * STR1))[d2] = pack_h2(b0, b1v);
            }
        }
    }
    __syncthreads();

    // ---- u/v precompute: uv[t<84] = 0.4att_h.gl1[j],  uv[84+..] = 0.4att_h.gr1[i] ----
    if (tid < 168) {
        int r = tid < 84 ? tid : tid - 84;
        int h = r / 21, idx = r - h * 21;
        const _Float16* rowp = (tid < 84 ? U.p1.gl1h : gr1h) + idx * STR1 + h * 64;
        const h8* row8 = (const h8*)rowp;
        const h2* ar = attLh + h * 32;
        float l0 = 0.f, l1 = 0.f;
        #pragma unroll
        for (int ch = 0; ch < 8; ++ch) {
            h8 g = row8[ch];
            l0 = fdot2(__builtin_shufflevector(g, g, 0, 1), ar[ch * 4 + 0], l0);
            l1 = fdot2(__builtin_shufflevector(g, g, 2, 3), ar[ch * 4 + 1], l1);
            l0 = fdot2(__builtin_shufflevector(g, g, 4, 5), ar[ch * 4 + 2], l0);
            l1 = fdot2(__builtin_shufflevector(g, g, 6, 7), ar[ch * 4 + 3], l1);
        }
        U.p1.uv[tid] = l0 + l1;
    }
    __syncthreads();

    // ---- layer-1 logits: abs part only (linear part added in softmax) ----
    {
        const int h = tid >> 6;           // wave-uniform head
        const int lane = tid & 63;
        h2 ar[32];
        #pragma unroll
        for (int q = 0; q < 32; ++q) ar[q] = attLh[h * 32 + q];

        for (int it = 0; it < 7; ++it) {
            int q = it * 64 + lane;
            if (q < 441) {
                int i = q / 21;
                int j = q - i * 21;
                const h8* gA8 = (const h8*)(U.p1.gl1h + j * STR1 + h * 64);
                const h8* gB8 = (const h8*)(gr1h + i * STR1 + h * 64);
                float m0 = 0.f, m1 = 0.f;
                #pragma unroll
                for (int ch = 0; ch < 8; ++ch) {
                    h8 x = gA8[ch] + gB8[ch];
                    h8 ax = habs8(x);
                    m0 = fdot2(__builtin_shufflevector(ax, ax, 0, 1), ar[ch * 4 + 0], m0);
                    m1 = fdot2(__builtin_shufflevector(ax, ax, 2, 3), ar[ch * 4 + 1], m1);
                    m0 = fdot2(__builtin_shufflevector(ax, ax, 4, 5), ar[ch * 4 + 2], m0);
                    m1 = fdot2(__builtin_shufflevector(ax, ax, 6, 7), ar[ch * 4 + 3], m1);
                }
                U.p1.eP[(h * 21 + i) * EPS + j] = m0 + m1;
            }
        }
    }
    __syncthreads();

    // ---- softmax-1: add linear part 1.5*(u_j + v_i), max/exp/pre-normalize ----
    if (tid < 84) {
        int h = tid / 21, i = tid - h * 21;
        float* row = U.p1.eP + tid * EPS;
        const float* uu = U.p1.uv + h * 21;
        float vi = 1.5f * U.p1.uv[84 + h * 21 + i];
        float ebuf[21];
        float m = -1e30f;
        #pragma unroll
        for (int j = 0; j < 21; j++) {
            float e = row[j] + 1.5f * uu[j] + vi;
            ebuf[j] = e;
            m = fmaxf(m, e);
        }
        float s = 0.f;
        #pragma unroll
        for (int j = 0; j < 21; j++) { float v = __expf(ebuf[j] - m); ebuf[j] = v; s += v; }
        float r = 1.f / s;
        #pragma unroll
        for (int j = 0; j < 21; j++) row[j] = ebuf[j] * r;
    }
    __syncthreads();

    // ---- layer-1 aggregation: thread = (head, channel); gl column in regs ----
    {
        // zero gr1h row 21 (A-tile-1 clamp target)
        if (tid < 33) {
            h8 zz = {(_Float16)0.f, (_Float16)0.f, (_Float16)0.f, (_Float16)0.f,
                     (_Float16)0.f, (_Float16)0.f, (_Float16)0.f, (_Float16)0.f};
            ((h8*)gr1h)[21 * 33 + tid] = zz;
        }
        const int h = tid >> 6, c = tid & 63;
        const int col = h * 64 + c;
        float glv[21];
        #pragma unroll
        for (int j = 0; j < 21; ++j) glv[j] = (float)U.p1.gl1h[j * STR1 + col];
        float bb = b1[col];
        for (int i = 0; i < 21; ++i) {
            const float4* ar4 = (const float4*)(U.p1.eP + (h * 21 + i) * EPS);
            float4 q0 = ar4[0], q1 = ar4[1], q2 = ar4[2], q3 = ar4[3], q4 = ar4[4];
            float a20 = U.p1.eP[(h * 21 + i) * EPS + 20];
            float acc;
            acc = q0.x * glv[0];
            acc = fmaf(q0.y, glv[1], acc);
            acc = fmaf(q0.z, glv[2], acc);
            acc = fmaf(q0.w, glv[3], acc);
            acc = fmaf(q1.x, glv[4], acc);
            acc = fmaf(q1.y, glv[5], acc);
            acc = fmaf(q1.z, glv[6], acc);
            acc = fmaf(q1.w, glv[7], acc);
            acc = fmaf(q2.x, glv[8], acc);
            acc = fmaf(q2.y, glv[9], acc);
            acc = fmaf(q2.z, glv[10], acc);
            acc = fmaf(q2.w, glv[11], acc);
            acc = fmaf(q3.x, glv[12], acc);
            acc = fmaf(q3.y, glv[13], acc);
            acc = fmaf(q3.z, glv[14], acc);
            acc = fmaf(q3.w, glv[15], acc);
            acc = fmaf(q4.x, glv[16], acc);
            acc = fmaf(q4.y, glv[17], acc);
            acc = fmaf(q4.z, glv[18], acc);
            acc = fmaf(q4.w, glv[19], acc);
            acc = fmaf(a20, glv[20], acc);
            float v = acc + bb;
            v = v > 0.f ? v : __expf(v) - 1.f;
            gr1h[i * STR1 + col] = (_Float16)v;
        }
    }
    __syncthreads();

    // ---- layer-2 transforms via MFMA 16x16x32 f16 ----
    {
        const int lane = tid & 63;
        const int w = tid >> 6;
        const int mrow = lane & 15;
        const int quad = lane >> 4;
        int rowA1 = 16 + mrow; if (rowA1 > 21) rowA1 = 21;   // rows >=21 are zero
        const h8* hA0 = (const h8*)(gr1h + mrow * STR1 + quad * 8);
        const h8* hA1 = (const h8*)(gr1h + rowA1 * STR1 + quad * 8);
        const h8* bL = wsL + w * 512 + lane;
        const h8* bR = wsR + w * 512 + lane;
        f32x4 aL0 = {0.f, 0.f, 0.f, 0.f}, aL1 = {0.f, 0.f, 0.f, 0.f};
        f32x4 aR0 = {0.f, 0.f, 0.f, 0.f}, aR1 = {0.f, 0.f, 0.f, 0.f};
        #pragma unroll
        for (int kc = 0; kc < 8; ++kc) {
            h8 A0 = hA0[kc * 4];
            h8 A1 = hA1[kc * 4];
            h8 BL = bL[kc * 64];
            h8 BR = bR[kc * 64];
            aL0 = mfma16(A0, BL, aL0);
            aL1 = mfma16(A1, BL, aL1);
            aR0 = mfma16(A0, BR, aR0);
            aR1 = mfma16(A1, BR, aR1);
        }
        const int col = w * 16 + mrow;
        #pragma unroll
        for (int r = 0; r < 4; ++r) {
            int row0 = quad * 4 + r;
            U.p2.gl2[row0 * STR2 + col] = aL0[r];
            U.p2.gl2h[row0 * STR2H + col] = (_Float16)aL0[r];
            U.p2.gr2h[row0 * STR2H + col] = (_Float16)aR0[r];
            int row1 = 16 + row0;
            if (row1 < 21) {
                U.p2.gl2[row1 * STR2 + col] = aL1[r];
                U.p2.gl2h[row1 * STR2H + col] = (_Float16)aL1[r];
                U.p2.gr2h[row1 * STR2H + col] = (_Float16)aR1[r];
            }
        }
    }
    __syncthreads();

    // ---- layer-2 logits (abs part, fp16) + u2/v2 in spare slots ----
    {
        h2 ar2[32];
        #pragma unroll
        for (int q = 0; q < 32; ++q) ar2[q] = att2Lh[q];

        #pragma unroll
        for (int it = 0; it < 2; ++it) {
            int t = it * 256 + tid;
            if (t < 441) {
                int i = t / 21;
                int j = t - i * 21;
                const h8* gA8 = (const h8*)(U.p2.gl2h + j * STR2H);
                const h8* gB8 = (const h8*)(U.p2.gr2h + i * STR2H);
                float m0 = 0.f, m1 = 0.f;
                #pragma unroll
                for (int ch = 0; ch < 8; ++ch) {
                    h8 x = gA8[ch] + gB8[ch];
                    h8 ax = habs8(x);
                    m0 = fdot2(__builtin_shufflevector(ax, ax, 0, 1), ar2[ch * 4 + 0], m0);
                    m1 = fdot2(__builtin_shufflevector(ax, ax, 2, 3), ar2[ch * 4 + 1], m1);
                    m0 = fdot2(__builtin_shufflevector(ax, ax, 4, 5), ar2[ch * 4 + 2], m0);
                    m1 = fdot2(__builtin_shufflevector(ax, ax, 6, 7), ar2[ch * 4 + 3], m1);
                }
                U.p2.e2[i * EPS2 + j] = m0 + m1;
            } else if (t < 483) {
                int u = t - 441;                  // 0..41
                int r = u < 21 ? u : u - 21;
                const _Float16* rowp = (u < 21 ? U.p2.gl2h : U.p2.gr2h) + r * STR2H;
                const h8* row8 = (const h8*)rowp;
                float l0 = 0.f, l1 = 0.f;
                #pragma unroll
                for (int ch = 0; ch < 8; ++ch) {
                    h8 g = row8[ch];
                    l0 = fdot2(__builtin_shufflevector(g, g, 0, 1), ar2[ch * 4 + 0], l0);
                    l1 = fdot2(__builtin_shufflevector(g, g, 2, 3), ar2[ch * 4 + 1], l1);
                    l0 = fdot2(__builtin_shufflevector(g, g, 4, 5), ar2[ch * 4 + 2], l0);
                    l1 = fdot2(__builtin_shufflevector(g, g, 6, 7), ar2[ch * 4 + 3], l1);
                }
                U.p2.u2v2[u] = l0 + l1;
            }
        }
    }
    __syncthreads();

    // ---- softmax-2: add linear, max/exp/pre-normalize; zero rows 21..23 ----
    if (tid < 24) {
        float* row = U.p2.e2 + tid * EPS2;
        if (tid < 21) {
            const float* uu = U.p2.u2v2;
            float vi = 1.5f * U.p2.u2v2[21 + tid];
            float ebuf[21];
            float m = -1e30f;
            #pragma unroll
            for (int j = 0; j < 21; j++) {
                float e = row[j] + 1.5f * uu[j] + vi;
                ebuf[j] = e;
                m = fmaxf(m, e);
            }
            float s = 0.f;
            #pragma unroll
            for (int j = 0; j < 21; j++) { float v = __expf(ebuf[j] - m); ebuf[j] = v; s += v; }
            float r = 1.f / s;
            #pragma unroll
            for (int j = 0; j < 21; j++) row[j] = ebuf[j] * r;
        } else {
            #pragma unroll
            for (int j = 0; j < 21; j++) row[j] = 0.f;
        }
    }
    __syncthreads();

    // ---- layer-2 aggregation: gl2 column in regs, b128 alpha rows ----
    {
        int d = tid & 63, g = tid >> 6;
        float glv2[21];
        #pragma unroll
        for (int j = 0; j < 21; ++j) glv2[j] = U.p2.gl2[j * STR2 + d];
        float sacc = 0.f;
        #pragma unroll
        for (int m = 0; m < 6; ++m) {
            int i = g + 4 * m;                  // 0..23; rows >=21 zero
            const float4* ar4 = (const float4*)(U.p2.e2 + i * EPS2);
            float4 q0 = ar4[0], q1 = ar4[1], q2 = ar4[2], q3 = ar4[3], q4 = ar4[4];
            float a20 = U.p2.e2[i * EPS2 + 20];
            float acc;
            acc = q0.x * glv2[0];
            acc = fmaf(q0.y, glv2[1], acc);
            acc = fmaf(q0.z, glv2[2], acc);
            acc = fmaf(q0.w, glv2[3], acc);
            acc = fmaf(q1.x, glv2[4], acc);
            acc = fmaf(q1.y, glv2[5], acc);
            acc = fmaf(q1.z, glv2[6], acc);
            acc = fmaf(q1.w, glv2[7], acc);
            acc = fmaf(q2.x, glv2[8], acc);
            acc = fmaf(q2.y, glv2[9], acc);
            acc = fmaf(q2.z, glv2[10], acc);
            acc = fmaf(q2.w, glv2[11], acc);
            acc = fmaf(q3.x, glv2[12], acc);
            acc = fmaf(q3.y, glv2[13], acc);
            acc = fmaf(q3.z, glv2[14], acc);
            acc = fmaf(q3.w, glv2[15], acc);
            acc = fmaf(q4.x, glv2[16], acc);
            acc = fmaf(q4.y, glv2[17], acc);
            acc = fmaf(q4.z, glv2[18], acc);
            acc = fmaf(q4.w, glv2[19], acc);
            acc = fmaf(a20, glv2[20], acc);
            sacc += acc;
        }
        U.p2.red[g][d] = sacc;
    }
    __syncthreads();
    if (tid < 64) {
        float v = (U.p2.red[0][tid] + U.p2.red[1][tid] + U.p2.red[2][tid] + U.p2.red[3][tid])
                  * (1.f / 21.f) + b2[tid];
        U.p2.nfvh[tid] = (_Float16)v;
    }
    __syncthreads();

    // ---- FC1 (64 -> 256): fp16 packed weights ----
    {
        int c = tid & 63, g = tid >> 6;
        const h2* x2p = (const h2*)U.p2.nfvh;
        float4 acc = {0.f, 0.f, 0.f, 0.f};
        #pragma unroll
        for (int kk = 0; kk < 8; ++kk) {
            int k2 = g * 8 + kk;
            h8 w = wsF1[k2 * 64 + c];
            h2 x2 = x2p[k2];
            acc.x = fdot2(__builtin_shufflevector(w, w, 0, 1), x2, acc.x);
            acc.y = fdot2(__builtin_shufflevector(w, w, 2, 3), x2, acc.y);
            acc.z = fdot2(__builtin_shufflevector(w, w, 4, 5), x2, acc.z);
            acc.w = fdot2(__builtin_shufflevector(w, w, 6, 7), x2, acc.w);
        }
        ((float4*)U.p2.red[g])[c] = acc;
    }
    __syncthreads();
    {
        float v = U.p2.red[0][tid] + U.p2.red[1][tid] + U.p2.red[2][tid] + U.p2.red[3][tid]
                  + fc1_b[tid];
        U.p2.hah[tid] = (_Float16)fmaxf(v, 0.f);
    }
    __syncthreads();

    // ---- FC2 (256 -> 256): fp16 packed weights + fp16 activations ----
    {
        int c = tid & 63, g = tid >> 6;
        const h8* haH = (const h8*)U.p2.hah;
        float4 acc = {0.f, 0.f, 0.f, 0.f};
#define FC2_STEP(q, p)                                                          \
        {                                                                       \
            int k2 = g * 32 + (q) * 4 + (p);                                    \
            h8 w = wsF2[k2 * 64 + c];                                           \
            h2 x2 = __builtin_shufflevector(xa, xa, 2 * (p), 2 * (p) + 1);      \
            acc.x = fdot2(__builtin_shufflevector(w, w, 0, 1), x2, acc.x);      \
            acc.y = fdot2(__builtin_shufflevector(w, w, 2, 3), x2, acc.y);      \
            acc.z = fdot2(__builtin_shufflevector(w, w, 4, 5), x2, acc.z);      \
            acc.w = fdot2(__builtin_shufflevector(w, w, 6, 7), x2, acc.w);      \
        }
        #pragma unroll
        for (int q = 0; q < 8; ++q) {
            h8 xa = haH[g * 8 + q];
            FC2_STEP(q, 0)
            FC2_STEP(q, 1)
            FC2_STEP(q, 2)
            FC2_STEP(q, 3)
        }
#undef FC2_STEP
        ((float4*)U.p2.red[g])[c] = acc;
    }
    __syncthreads();
    {
        float v = U.p2.red[0][tid] + U.p2.red[1][tid] + U.p2.red[2][tid] + U.p2.red[3][tid]
                  + fc2_b[tid];
        U.p2.hbh[tid] = (_Float16)fmaxf(v, 0.f);
    }
    __syncthreads();

    // ---- FC3 (256 -> 2) + tanh ----
    if (tid < 128) {
        int o = tid >> 6, l = tid & 63;
        float s = 0.f;
        #pragma unroll
        for (int m = 0; m < 4; m++) {
            int k = l + 64 * m;
            s = fmaf((float)U.p2.hbh[k], fc3_w[k * 2 + o], s);
        }
        #pragma unroll
        for (int off = 32; off >= 1; off >>= 1) s += __shfl_down(s, off, 64);
        if (l == 0) out[bix * 2 + o] = tanhf(s + fc3_b[o]);
    }
}

extern "C" void kernel_launch(void* const* d_in, const int* in_sizes, int n_in,
                              void* d_out, int out_size, void* d_ws, size_t ws_size,
                              hipStream_t stream) {
    const float* state24 = (const float*)d_in[0];
    const float* Wl1 = (const float*)d_in[1];
    const float* Wr1 = (const float*)d_in[2];
    const float* att1 = (const float*)d_in[3];
    const float* b1 = (const float*)d_in[4];
    const float* Wl2 = (const float*)d_in[5];
    const float* Wr2 = (const float*)d_in[6];
    const float* att2 = (const float*)d_in[7];
    const float* b2 = (const float*)d_in[8];
    const float* fc1_w = (const float*)d_in[9];
    const float* fc1_b = (const float*)d_in[10];
    const float* fc2_w = (const float*)d_in[11];
    const float* fc2_b = (const float*)d_in[12];
    const float* fc3_w = (const float*)d_in[13];
    const float* fc3_b = (const float*)d_in[14];
    float* out = (float*)d_out;

    h8* ws = (h8*)d_ws;                 // 14336 h8 = 224 KiB
    const h8* wsL = ws;
    const h8* wsR = ws + 2048;
    const h8* wsF1 = ws + 4096;
    const h8* wsF2 = ws + 6144;

    pack_weights_kernel<<<56, 256, 0, stream>>>(Wl2, Wr2, fc1_w, fc2_w, ws);

    int B = in_sizes[0] / 24;
    actor_fused_kernel<<<B, 256, 0, stream>>>(
        state24, Wl1, Wr1, att1, b1, att2, b2,
        fc1_b, fc2_b, fc3_w, fc3_b,
        wsL, wsR, wsF1, wsF2, out, B);
}